// Round 8
// baseline (191.953 us; speedup 1.0000x reference)
//
#include <hip/hip_runtime.h>
#include <stdint.h>

// ---------------------------------------------------------------------------
// BertSelfAttention (relative_key_query) on gfx950.
// B=4 S=1024 H=768 nH=12 dH=64 MAXPOS=1024.
//   q,k,v = hidden @ W{q,k,v}.T + b        (bf16 MFMA GEMM)
//   S[l,r] = q.k + q.E[l-r+1023] + k.E[l-r+1023];  softmax(S/8 + mask) @ v
// Pipeline: convert(fp32->bf16) -> qkv_gemm -> fused flash attention.
// v9:
//   - qkv_gemm back to 128x128 grid (32,18) (R7's 128x96 raised A refetch,
//     -6us) + the v6 pipeline treatment: double-buffered LDS (64KB, 2
//     blocks/CU), ONE barrier/iter, stage(kit+1) issued after this iter's
//     ds_reads so MFMA covers the load latency; XCD-chunk swizzle (576=8*72).
//   - attn/convert frozen at R7 (attn 89.2us, no spill).
// ---------------------------------------------------------------------------

typedef __attribute__((ext_vector_type(4))) float f32x4;
typedef __attribute__((ext_vector_type(8))) short s16x8;
typedef __attribute__((ext_vector_type(4))) short s16x4;
typedef const __attribute__((address_space(1))) void GCV;
typedef __attribute__((address_space(3))) void LDSV;

__device__ __forceinline__ unsigned short f2bf(float f) {
  union { float f; uint32_t u; } v; v.f = f;
  uint32_t r = (v.u + 0x7FFFu + ((v.u >> 16) & 1u)) >> 16;
  return (unsigned short)r;
}
__device__ __forceinline__ float bf2f(unsigned short b) {
  union { uint32_t u; float f; } v; v.u = ((uint32_t)b) << 16;
  return v.f;
}
__device__ __forceinline__ uint32_t packbf(float a, float b) {
  return (uint32_t)f2bf(a) | ((uint32_t)f2bf(b) << 16);
}

#define MFMA(a, b, c) __builtin_amdgcn_mfma_f32_16x16x32_bf16((a), (b), (c), 0, 0, 0)

// ---------------------------------------------------------------------------
// Kernel 0: fp32 -> bf16 conversion. hidden [4096x768], Wq|Wk|Wv [768x768]x3,
// dist_emb [2047x64] padded to 2048 rows (row 2047 = 0).
// ---------------------------------------------------------------------------
#define HIDQ 786432   // 4096*768/4
#define WQ4  147456   // 768*768/4
#define EQ4  32768    // 2048*64/4

__global__ __launch_bounds__(256) void convert_kernel(
    const float* __restrict__ hid, const float* __restrict__ wq,
    const float* __restrict__ wk, const float* __restrict__ wv,
    const float* __restrict__ de,
    unsigned short* __restrict__ hidbf, unsigned short* __restrict__ wbf,
    unsigned short* __restrict__ ebf) {
  int g = blockIdx.x * 256 + threadIdx.x;
  if (g < HIDQ) {
    float4 s = ((const float4*)hid)[g];
    ushort4 o; o.x = f2bf(s.x); o.y = f2bf(s.y); o.z = f2bf(s.z); o.w = f2bf(s.w);
    ((ushort4*)hidbf)[g] = o;
  } else if (g < HIDQ + 3 * WQ4) {
    int r = g - HIDQ;
    int sel = r / WQ4, r2 = r - sel * WQ4;
    const float* src = sel == 0 ? wq : (sel == 1 ? wk : wv);
    float4 s = ((const float4*)src)[r2];
    ushort4 o; o.x = f2bf(s.x); o.y = f2bf(s.y); o.z = f2bf(s.z); o.w = f2bf(s.w);
    ((ushort4*)wbf)[r] = o;
  } else {
    int r = g - HIDQ - 3 * WQ4;      // [0, 32768)
    int e = 4 * r;                   // element index into 2048*64
    ushort4 o;
    o.x = (e + 0 < 131008) ? f2bf(de[e + 0]) : 0;
    o.y = (e + 1 < 131008) ? f2bf(de[e + 1]) : 0;
    o.z = (e + 2 < 131008) ? f2bf(de[e + 2]) : 0;
    o.w = (e + 3 < 131008) ? f2bf(de[e + 3]) : 0;
    ((ushort4*)ebf)[r] = o;
  }
}

// ---------------------------------------------------------------------------
// Kernel 1: QKV projection GEMM.  C[m, o] = sum_i hid[m,i] * W[o,i] + bias[o]
// M=4096, N=2304 (q|k|v), K=768. 128x128 tile, BK=64, 4 waves (64x64 each).
// Double-buffered LDS; stage(kit+1) issued after this iter's ds_reads so the
// MFMA block covers load latency; ONE barrier per K-iter. XCD-chunk swizzle.
// Outputs: q,k -> [bh][s][64] bf16 ; v -> transposed [bh][d][1024] bf16.
// ---------------------------------------------------------------------------
__global__ __launch_bounds__(256, 2) void qkv_gemm(
    const unsigned short* __restrict__ hidbf,   // [4096][768]
    const unsigned short* __restrict__ wbf,     // [3][768][768]
    const float* __restrict__ bq, const float* __restrict__ bk,
    const float* __restrict__ bv,
    unsigned short* __restrict__ qb, unsigned short* __restrict__ kb,
    unsigned short* __restrict__ vtb) {
  __shared__ unsigned short lda[2][128 * 64];   // 32KB, xor-swizzled 16B chunks
  __shared__ unsigned short ldb[2][128 * 64];   // 32KB
  const int tid = threadIdx.x;
  const int w = tid >> 6, lane = tid & 63, quad = lane >> 4, l15 = lane & 15;
  // XCD-chunk swizzle: 576 blocks = 8 XCDs x 72 consecutive (bijective).
  const int lin = blockIdx.x + (blockIdx.y << 5);
  const int nl = (lin & 7) * 72 + (lin >> 3);
  const int m0 = (nl & 31) * 128;
  const int bn = nl >> 5;                    // [0,18)
  const int sel = bn / 6;
  const int nc0 = (bn - sel * 6) * 128;
  const unsigned short* wsrc = wbf + (size_t)sel * 589824;

  f32x4 acc[4][4];
#pragma unroll
  for (int i = 0; i < 4; ++i)
#pragma unroll
    for (int j = 0; j < 4; ++j) acc[i][j] = (f32x4){0.f, 0.f, 0.f, 0.f};

  const int rA = 64 * (w & 1);
  const int rB = 64 * (w >> 1);

  // stage A,B tile kit into buffer buf: [128 rows][64 bf16], xor swizzle
  auto stage = [&](int kit, int buf) {
    const int k0 = kit * 64;
#pragma unroll
    for (int i = 0; i < 4; ++i) {
      int cl = (w * 4 + i) * 64 + lane;
      int row = cl >> 3, cp = cl & 7, gch = cp ^ (row & 7);
      __builtin_amdgcn_global_load_lds(
          (GCV*)(hidbf + (size_t)(m0 + row) * 768 + k0 + gch * 8),
          (LDSV*)(&lda[buf][0] + (size_t)(w * 4 + i) * 512), 16, 0, 0);
      __builtin_amdgcn_global_load_lds(
          (GCV*)(wsrc + (size_t)(nc0 + row) * 768 + k0 + gch * 8),
          (LDSV*)(&ldb[buf][0] + (size_t)(w * 4 + i) * 512), 16, 0, 0);
    }
  };

  stage(0, 0);   // prologue

  for (int kit = 0; kit < 12; ++kit) {
    const int buf = kit & 1;
    // drains vmcnt: buf(kit) staged data visible; all waves done reading
    // buf^1 (iter kit-1) so it is free to overwrite.
    __syncthreads();

    s16x8 af[4][2], bfr[4][2];
#pragma unroll
    for (int mt = 0; mt < 4; ++mt)
#pragma unroll
      for (int ks = 0; ks < 2; ++ks) {
        int row = rA + 16 * mt + l15;
        af[mt][ks] = *(const s16x8*)(&lda[buf][0] + row * 64 + (((quad + 4 * ks) ^ (row & 7)) * 8));
        int rowb = rB + 16 * mt + l15;
        bfr[mt][ks] = *(const s16x8*)(&ldb[buf][0] + rowb * 64 + (((quad + 4 * ks) ^ (rowb & 7)) * 8));
      }

    // issue next tile's stage now: its latency is covered by the MFMAs below
    // and drained at the next top-of-loop barrier.
    if (kit < 11) stage(kit + 1, buf ^ 1);

#pragma unroll
    for (int mt = 0; mt < 4; ++mt)
#pragma unroll
      for (int nt = 0; nt < 4; ++nt) {
        acc[mt][nt] = MFMA(af[mt][0], bfr[nt][0], acc[mt][nt]);
        acc[mt][nt] = MFMA(af[mt][1], bfr[nt][1], acc[mt][nt]);
      }
  }

  const float* bias = sel == 0 ? bq : (sel == 1 ? bk : bv);
#pragma unroll
  for (int nt = 0; nt < 4; ++nt) {
    int oc = nc0 + rB + 16 * nt + l15;          // [0,768)
    float bvl = bias[oc];
    int h = oc >> 6, dd = oc & 63;
#pragma unroll
    for (int mt = 0; mt < 4; ++mt) {
      int mbase = m0 + rA + 16 * mt + quad * 4;
      int b = mbase >> 10, s = mbase & 1023;
      size_t bh = (size_t)(b * 12 + h);
      if (sel < 2) {
        unsigned short* dst = (sel == 0 ? qb : kb) + bh * 65536 + (size_t)s * 64 + dd;
#pragma unroll
        for (int r = 0; r < 4; ++r) dst[(size_t)r * 64] = f2bf(acc[mt][nt][r] + bvl);
      } else {
        ushort4 pk;
        pk.x = f2bf(acc[mt][nt][0] + bvl); pk.y = f2bf(acc[mt][nt][1] + bvl);
        pk.z = f2bf(acc[mt][nt][2] + bvl); pk.w = f2bf(acc[mt][nt][3] + bvl);
        *(ushort4*)(vtb + bh * 65536 + (size_t)dd * 1024 + s) = pk;
      }
    }
  }
}

// ---------------------------------------------------------------------------
// Kernel 2: fused attention. One block = (bh, 64 q-rows). 4 waves, wave w owns
// i-strip [16w,16w+16). S computed TRANSPOSED (A=k,B=q): lane holds
// St[j=16mt+4q+r][i=l15]. Bias GEMMs Qe=q@E^T (per-wave) and Ke=k@E^T (coop)
// store SHEARED [i][j] so the softmax gather is aligned s16x4. Max-free
// online softmax. PV via P through per-wave LDS (aliases Qe region).
// ---------------------------------------------------------------------------
__global__ __launch_bounds__(256, 3) void attn_kernel(
    const unsigned short* __restrict__ qb, const unsigned short* __restrict__ kb,
    const unsigned short* __restrict__ vtb, const unsigned short* __restrict__ ebf,
    const float* __restrict__ mask, float* __restrict__ out) {
  __shared__ unsigned short ksw[64 * 64];        // 8KB   swizzled
  __shared__ unsigned short vsw[64 * 64];        // 8KB   swizzled (rows = d)
  __shared__ unsigned short esw[128 * 64];       // 16KB  swizzled (rows = t)
  __shared__ unsigned short keS[64 * 68];        // 8.5KB sheared Ke[i][j], stride 68
  __shared__ unsigned short qp[4][16 * 72];      // 9KB   per-wave sheared Qe[i][j] / P[i][j]
  __shared__ unsigned short mlb[1024];           // 2KB   mask row * log2(e), bf16
  // total 51.5KB -> 3 blocks/CU

  const int tid = threadIdx.x;
  const int w = tid >> 6, lane = tid & 63, quad = lane >> 4, l15 = lane & 15;
  const int blk0 = blockIdx.x;
  const int blk = (blk0 & 7) * 96 + (blk0 >> 3);   // XCD-bijective (768 = 8*96):
  const int bh = blk >> 4;                         // all 16 l-tiles of a bh on one XCD
  const int l0 = (blk & 15) << 6;
  const int b = bh / 12;
  const int h = bh - b * 12;

  const float SC1 = 0.18033688f;   // log2(e)/8
  const float SC2 = 1.44269504f;   // log2(e)

  const unsigned short* kbh = kb + (size_t)bh * 65536;
  const unsigned short* vbh = vtb + (size_t)bh * 65536;
  unsigned short* qpw = &qp[w][0];

  // ---- staging helpers (async global->LDS, 16B/lane, xor-swizzled chunks)
  auto stage_k = [&](int r0) {
    const unsigned short* kbase = kbh + (size_t)r0 * 64;
#pragma unroll
    for (int i = 0; i < 2; ++i) {
      int cl = (w * 2 + i) * 64 + lane;
      int row = cl >> 3, cp = cl & 7, gch = cp ^ (row & 7);
      __builtin_amdgcn_global_load_lds((GCV*)(kbase + row * 64 + gch * 8),
                                       (LDSV*)(ksw + (size_t)(w * 2 + i) * 512), 16, 0, 0);
    }
  };
  auto stage_v = [&](int r0) {
    const unsigned short* vbase = vbh + r0;
#pragma unroll
    for (int i = 0; i < 2; ++i) {
      int cl = (w * 2 + i) * 64 + lane;
      int row = cl >> 3, cp = cl & 7, gch = cp ^ (row & 7);
      __builtin_amdgcn_global_load_lds((GCV*)(vbase + (size_t)row * 1024 + gch * 8),
                                       (LDSV*)(vsw + (size_t)(w * 2 + i) * 512), 16, 0, 0);
    }
  };
  auto stage_e = [&](int dbase) {
    const unsigned short* ebase = ebf + (size_t)dbase * 64;
#pragma unroll
    for (int i = 0; i < 4; ++i) {
      int cl = (w * 4 + i) * 64 + lane;
      int row = cl >> 3, cp = cl & 7, gch = cp ^ (row & 7);
      __builtin_amdgcn_global_load_lds((GCV*)(ebase + row * 64 + gch * 8),
                                       (LDSV*)(esw + (size_t)(w * 4 + i) * 512), 16, 0, 0);
    }
  };

  // stage mask row (pre-scaled by log2e, bf16); ordered by first top barrier
  {
    float4 mv = ((const float4*)(mask + (size_t)b * 1024))[tid];
    ushort4 ms;
    ms.x = f2bf(mv.x * SC2); ms.y = f2bf(mv.y * SC2);
    ms.z = f2bf(mv.z * SC2); ms.w = f2bf(mv.w * SC2);
    *(ushort4*)(mlb + tid * 4) = ms;
  }

  // q B-frags for strip row l0+16w+l15 (held all 16 iters)
  const unsigned short* qrow = qb + (size_t)bh * 65536 + (size_t)(l0 + 16 * w + l15) * 64;
  s16x8 qf[2];
  qf[0] = *(const s16x8*)(qrow + quad * 8);
  qf[1] = *(const s16x8*)(qrow + 32 + quad * 8);

  f32x4 oacc[4];
#pragma unroll
  for (int i = 0; i < 4; ++i) oacc[i] = (f32x4){0.f, 0.f, 0.f, 0.f};
  float lsum = 0.f;

  // ---- prologue: stage k/E for it=0
  stage_k(0);
  stage_e(l0 + 960);

  for (int it = 0; it < 16; ++it) {
    const int r0 = it << 6;
    __syncthreads();   // top: k/E(it) ready (vmcnt drain); all prev-iter PV reads done
    stage_v(r0);       // into single-buffer vsw; latency covered by phase1

    // ---- phase1: k A-frags (feed St and Ke)
    s16x8 kf[4][2];
#pragma unroll
    for (int mt = 0; mt < 4; ++mt)
#pragma unroll
      for (int ks = 0; ks < 2; ++ks) {
        int row = 16 * mt + l15;
        kf[mt][ks] = *(const s16x8*)(ksw + row * 64 + (((quad + 4 * ks) ^ (row & 7)) * 8));
      }

    // ---- St[j][i] = k . q
    __builtin_amdgcn_s_setprio(1);
    f32x4 st[4];
#pragma unroll
    for (int mt = 0; mt < 4; ++mt) {
      f32x4 a = (f32x4){0.f, 0.f, 0.f, 0.f};
      a = MFMA(kf[mt][0], qf[0], a);
      a = MFMA(kf[mt][1], qf[1], a);
      st[mt] = a;
    }
    __builtin_amdgcn_s_setprio(0);

    // ---- Qe (wave window t-tiles [w, w+4]): a[r] is Qe at
    //   (i_local = 4*quad + r, t = 16*(w+tp) + l15);  sheared col
    //   j = i + 63 - t = (4*quad + r) + 63 - 16*tp - l15   (w cancels).
    // Ke piggybacks on tp==w, w+1 (wave-uniform; tiles tt = 2w, 2w+1):
    //   ka[r] is Ke at (t = 16*tt + l15, j = 16*mt + 4*quad + r);
    //   sheared row i = t + j - 63.
#pragma unroll
    for (int tp = 0; tp < 5; ++tp) {
      int tt = w + tp;
      int row = 16 * tt + l15;
      s16x8 ef0 = *(const s16x8*)(esw + row * 64 + ((quad ^ (row & 7)) * 8));
      s16x8 ef1 = *(const s16x8*)(esw + row * 64 + (((quad + 4) ^ (row & 7)) * 8));
      __builtin_amdgcn_s_setprio(1);
      f32x4 a = (f32x4){0.f, 0.f, 0.f, 0.f};
      a = MFMA(qf[0], ef0, a);
      a = MFMA(qf[1], ef1, a);
      __builtin_amdgcn_s_setprio(0);
#pragma unroll
      for (int r = 0; r < 4; ++r) {
        int j = 4 * quad + r + 63 - 16 * tp - l15;
        if ((unsigned)j < 64u) qpw[(4 * quad + r) * 72 + j] = f2bf(a[r]);
      }
      if (tp == w || tp == w + 1) {
#pragma unroll
        for (int mt = 0; mt < 4; ++mt) {
          __builtin_amdgcn_s_setprio(1);
          f32x4 kacc = (f32x4){0.f, 0.f, 0.f, 0.f};
          kacc = MFMA(kf[mt][0], ef0, kacc);
          kacc = MFMA(kf[mt][1], ef1, kacc);
          __builtin_amdgcn_s_setprio(0);
          int jb = 16 * mt + 4 * quad;
          int ib0 = 16 * tt + l15 + jb - 63;
#pragma unroll
          for (int r = 0; r < 4; ++r) {
            int ii = ib0 + r;
            if ((unsigned)ii < 64u) keS[ii * 68 + jb + r] = f2bf(kacc[r]);
          }
        }
      }
    }
    __syncthreads();   // mid: drains vmcnt (vsw ready); keS/qp visible block-wide

    // ---- issue stage k/E for it+1 (drained at next top barrier; phase2
    // below covers the latency)
    if (it < 15) {
      stage_k(r0 + 64);
      stage_e(l0 - r0 - 64 + 960);
    }

    // ---- phase2: softmax — sheared bias rows are plain [i][j]: aligned s16x4
    float pr[4][4];
#pragma unroll
    for (int mt = 0; mt < 4; ++mt) {
      int jb = 16 * mt + 4 * quad;
      s16x4 qv4 = *(const s16x4*)(qpw + l15 * 72 + jb);
      s16x4 kv4 = *(const s16x4*)(keS + (16 * w + l15) * 68 + jb);
      s16x4 mk4 = *(const s16x4*)(mlb + r0 + jb);
#pragma unroll
      for (int r = 0; r < 4; ++r) {
        float bias = bf2f((unsigned short)qv4[r]) + bf2f((unsigned short)kv4[r]);
        float p = exp2f((st[mt][r] + bias) * SC1 + bf2f((unsigned short)mk4[r]));
        pr[mt][r] = p;
        lsum += p;
      }
    }

    // ---- P -> per-wave LDS [i=l15][j] (b64 stores; same cells the thread
    // just read as qv4 -> per-thread RAW order holds), then A-frags
#pragma unroll
    for (int mt = 0; mt < 4; ++mt) {
      uint2 pk; pk.x = packbf(pr[mt][0], pr[mt][1]); pk.y = packbf(pr[mt][2], pr[mt][3]);
      *(uint2*)(qpw + l15 * 72 + 16 * mt + 4 * quad) = pk;
    }
    s16x8 pf0 = *(const s16x8*)(qpw + l15 * 72 + quad * 8);
    s16x8 pf1 = *(const s16x8*)(qpw + l15 * 72 + 32 + quad * 8);

    // ---- O += P @ V  (B-frags from transposed V in LDS)
    __builtin_amdgcn_s_setprio(1);
#pragma unroll
    for (int dt = 0; dt < 4; ++dt) {
      int row = 16 * dt + l15;
      s16x8 vf0 = *(const s16x8*)(vsw + row * 64 + ((quad ^ (row & 7)) * 8));
      s16x8 vf1 = *(const s16x8*)(vsw + row * 64 + (((quad + 4) ^ (row & 7)) * 8));
      oacc[dt] = MFMA(pf0, vf0, oacc[dt]);
      oacc[dt] = MFMA(pf1, vf1, oacc[dt]);
    }
    __builtin_amdgcn_s_setprio(0);
  }

  // ---- finalize: row sums live per-lane (i=l15); combine quads, divide, store
  lsum += __shfl_xor(lsum, 16, 64);
  lsum += __shfl_xor(lsum, 32, 64);
#pragma unroll
  for (int r = 0; r < 4; ++r) {
    float ls = __shfl(lsum, quad * 4 + r, 64);
    float rinv = 1.0f / ls;
    int l = l0 + 16 * w + quad * 4 + r;
    float* dst = out + ((size_t)(b * 1024 + l)) * 768 + h * 64;
#pragma unroll
    for (int dt = 0; dt < 4; ++dt) dst[16 * dt + l15] = oacc[dt][r] * rinv;
  }
}

// ---------------------------------------------------------------------------
extern "C" void kernel_launch(void* const* d_in, const int* in_sizes, int n_in,
                              void* d_out, int out_size, void* d_ws, size_t ws_size,
                              hipStream_t stream) {
  const float* hid  = (const float*)d_in[0];
  const float* mask = (const float*)d_in[1];
  const float* wq   = (const float*)d_in[2];
  const float* bq   = (const float*)d_in[3];
  const float* wk   = (const float*)d_in[4];
  const float* bk   = (const float*)d_in[5];
  const float* wv   = (const float*)d_in[6];
  const float* bv   = (const float*)d_in[7];
  const float* de   = (const float*)d_in[8];

  char* ws = (char*)d_ws;
  unsigned short* hidbf = (unsigned short*)(ws);                  // 6,291,456 B
  unsigned short* wbf   = (unsigned short*)(ws + 6291456);        // 3,538,944 B
  unsigned short* ebf   = (unsigned short*)(ws + 9830400);        //   262,144 B
  unsigned short* qb    = (unsigned short*)(ws + 10092544);       // 6,291,456 B
  unsigned short* kb    = (unsigned short*)(ws + 16384000);       // 6,291,456 B
  unsigned short* vtb   = (unsigned short*)(ws + 22675456);       // 6,291,456 B

  convert_kernel<<<4928, 256, 0, stream>>>(hid, wq, wk, wv, de, hidbf, wbf, ebf);
  qkv_gemm<<<dim3(32, 18), 256, 0, stream>>>(hidbf, wbf, bq, bk, bv, qb, kb, vtb);
  attn_kernel<<<768, 256, 0, stream>>>(qb, kb, vtb, ebf, mask, (float*)d_out);
}

// Round 9
// 181.369 us; speedup vs baseline: 1.0584x; 1.0584x over previous
//
#include <hip/hip_runtime.h>
#include <stdint.h>

// ---------------------------------------------------------------------------
// BertSelfAttention (relative_key_query) on gfx950.
// B=4 S=1024 H=768 nH=12 dH=64 MAXPOS=1024.
//   q,k,v = hidden @ W{q,k,v}.T + b        (bf16 MFMA GEMM)
//   S[l,r] = q.k + q.E[l-r+1023] + k.E[l-r+1023];  softmax(S/8 + mask) @ v
// Pipeline: convert(fp32->bf16) -> qkv_gemm -> fused flash attention.
// v10:
//   - qkv_gemm reverted to R6-exact (128x128 grid (32,18), 2-barrier,
//     single-buffer 32KB LDS, no swizzle): R8's dbuf+swizzle cost 9us
//     (64KB LDS halved occupancy; MFMA block too short to cover loads).
//   - attn: ALL s_setprio pairs removed. m190 evidence: setprio hurts
//     barrier-synced lockstep blocks (ours is 4-wave lockstep, not m191's
//     independent-wave attn); 10 asm pairs/iter also fence the scheduler,
//     blocking ef-ds_read/MFMA/store interleave across the tp loop.
// ---------------------------------------------------------------------------

typedef __attribute__((ext_vector_type(4))) float f32x4;
typedef __attribute__((ext_vector_type(8))) short s16x8;
typedef __attribute__((ext_vector_type(4))) short s16x4;
typedef const __attribute__((address_space(1))) void GCV;
typedef __attribute__((address_space(3))) void LDSV;

__device__ __forceinline__ unsigned short f2bf(float f) {
  union { float f; uint32_t u; } v; v.f = f;
  uint32_t r = (v.u + 0x7FFFu + ((v.u >> 16) & 1u)) >> 16;
  return (unsigned short)r;
}
__device__ __forceinline__ float bf2f(unsigned short b) {
  union { uint32_t u; float f; } v; v.u = ((uint32_t)b) << 16;
  return v.f;
}
__device__ __forceinline__ uint32_t packbf(float a, float b) {
  return (uint32_t)f2bf(a) | ((uint32_t)f2bf(b) << 16);
}

#define MFMA(a, b, c) __builtin_amdgcn_mfma_f32_16x16x32_bf16((a), (b), (c), 0, 0, 0)

// ---------------------------------------------------------------------------
// Kernel 0: fp32 -> bf16 conversion. hidden [4096x768], Wq|Wk|Wv [768x768]x3,
// dist_emb [2047x64] padded to 2048 rows (row 2047 = 0).
// ---------------------------------------------------------------------------
#define HIDQ 786432   // 4096*768/4
#define WQ4  147456   // 768*768/4
#define EQ4  32768    // 2048*64/4

__global__ __launch_bounds__(256) void convert_kernel(
    const float* __restrict__ hid, const float* __restrict__ wq,
    const float* __restrict__ wk, const float* __restrict__ wv,
    const float* __restrict__ de,
    unsigned short* __restrict__ hidbf, unsigned short* __restrict__ wbf,
    unsigned short* __restrict__ ebf) {
  int g = blockIdx.x * 256 + threadIdx.x;
  if (g < HIDQ) {
    float4 s = ((const float4*)hid)[g];
    ushort4 o; o.x = f2bf(s.x); o.y = f2bf(s.y); o.z = f2bf(s.z); o.w = f2bf(s.w);
    ((ushort4*)hidbf)[g] = o;
  } else if (g < HIDQ + 3 * WQ4) {
    int r = g - HIDQ;
    int sel = r / WQ4, r2 = r - sel * WQ4;
    const float* src = sel == 0 ? wq : (sel == 1 ? wk : wv);
    float4 s = ((const float4*)src)[r2];
    ushort4 o; o.x = f2bf(s.x); o.y = f2bf(s.y); o.z = f2bf(s.z); o.w = f2bf(s.w);
    ((ushort4*)wbf)[r] = o;
  } else {
    int r = g - HIDQ - 3 * WQ4;      // [0, 32768)
    int e = 4 * r;                   // element index into 2048*64
    ushort4 o;
    o.x = (e + 0 < 131008) ? f2bf(de[e + 0]) : 0;
    o.y = (e + 1 < 131008) ? f2bf(de[e + 1]) : 0;
    o.z = (e + 2 < 131008) ? f2bf(de[e + 2]) : 0;
    o.w = (e + 3 < 131008) ? f2bf(de[e + 3]) : 0;
    ((ushort4*)ebf)[r] = o;
  }
}

// ---------------------------------------------------------------------------
// Kernel 1: QKV projection GEMM.  C[m, o] = sum_i hid[m,i] * W[o,i] + bias[o]
// M=4096, N=2304 (q|k|v), K=768. 128x128 tile, BK=64, 4 waves (64x64 each).
// (R6-exact structure: single-buffer LDS, 2 barriers/iter.)
// Outputs: q,k -> [bh][s][64] bf16 ; v -> transposed [bh][d][1024] bf16.
// ---------------------------------------------------------------------------
__global__ __launch_bounds__(256, 2) void qkv_gemm(
    const unsigned short* __restrict__ hidbf,   // [4096][768]
    const unsigned short* __restrict__ wbf,     // [3][768][768]
    const float* __restrict__ bq, const float* __restrict__ bk,
    const float* __restrict__ bv,
    unsigned short* __restrict__ qb, unsigned short* __restrict__ kb,
    unsigned short* __restrict__ vtb) {
  __shared__ unsigned short lda[128 * 64];   // 16KB, xor-swizzled 16B chunks
  __shared__ unsigned short ldb[128 * 64];   // 16KB
  const int tid = threadIdx.x;
  const int w = tid >> 6, lane = tid & 63, quad = lane >> 4, l15 = lane & 15;
  const int m0 = blockIdx.x * 128;
  const int bn = blockIdx.y;
  const int sel = bn / 6;
  const int nc0 = (bn - sel * 6) * 128;
  const unsigned short* wsrc = wbf + (size_t)sel * 589824;

  f32x4 acc[4][4];
#pragma unroll
  for (int i = 0; i < 4; ++i)
#pragma unroll
    for (int j = 0; j < 4; ++j) acc[i][j] = (f32x4){0.f, 0.f, 0.f, 0.f};

  const int rA = 64 * (w & 1);
  const int rB = 64 * (w >> 1);

  for (int kit = 0; kit < 12; ++kit) {
    int k0 = kit * 64;
    __syncthreads();
    // stage A,B: [128 rows][64 bf16]; chunk-linear = row*8 + cpos, xor swizzle
#pragma unroll
    for (int i = 0; i < 4; ++i) {
      int cl = (w * 4 + i) * 64 + lane;
      int row = cl >> 3, cp = cl & 7, gch = cp ^ (row & 7);
      __builtin_amdgcn_global_load_lds(
          (GCV*)(hidbf + (size_t)(m0 + row) * 768 + k0 + gch * 8),
          (LDSV*)(lda + (size_t)(w * 4 + i) * 512), 16, 0, 0);
      __builtin_amdgcn_global_load_lds(
          (GCV*)(wsrc + (size_t)(nc0 + row) * 768 + k0 + gch * 8),
          (LDSV*)(ldb + (size_t)(w * 4 + i) * 512), 16, 0, 0);
    }
    __syncthreads();

    s16x8 af[4][2], bfr[4][2];
#pragma unroll
    for (int mt = 0; mt < 4; ++mt)
#pragma unroll
      for (int ks = 0; ks < 2; ++ks) {
        int row = rA + 16 * mt + l15;
        af[mt][ks] = *(const s16x8*)(lda + row * 64 + (((quad + 4 * ks) ^ (row & 7)) * 8));
        int rowb = rB + 16 * mt + l15;
        bfr[mt][ks] = *(const s16x8*)(ldb + rowb * 64 + (((quad + 4 * ks) ^ (rowb & 7)) * 8));
      }
#pragma unroll
    for (int mt = 0; mt < 4; ++mt)
#pragma unroll
      for (int nt = 0; nt < 4; ++nt) {
        acc[mt][nt] = MFMA(af[mt][0], bfr[nt][0], acc[mt][nt]);
        acc[mt][nt] = MFMA(af[mt][1], bfr[nt][1], acc[mt][nt]);
      }
  }

  const float* bias = sel == 0 ? bq : (sel == 1 ? bk : bv);
#pragma unroll
  for (int nt = 0; nt < 4; ++nt) {
    int oc = nc0 + rB + 16 * nt + l15;          // [0,768)
    float bvl = bias[oc];
    int h = oc >> 6, dd = oc & 63;
#pragma unroll
    for (int mt = 0; mt < 4; ++mt) {
      int mbase = m0 + rA + 16 * mt + quad * 4;
      int b = mbase >> 10, s = mbase & 1023;
      size_t bh = (size_t)(b * 12 + h);
      if (sel < 2) {
        unsigned short* dst = (sel == 0 ? qb : kb) + bh * 65536 + (size_t)s * 64 + dd;
#pragma unroll
        for (int r = 0; r < 4; ++r) dst[(size_t)r * 64] = f2bf(acc[mt][nt][r] + bvl);
      } else {
        ushort4 pk;
        pk.x = f2bf(acc[mt][nt][0] + bvl); pk.y = f2bf(acc[mt][nt][1] + bvl);
        pk.z = f2bf(acc[mt][nt][2] + bvl); pk.w = f2bf(acc[mt][nt][3] + bvl);
        *(ushort4*)(vtb + bh * 65536 + (size_t)dd * 1024 + s) = pk;
      }
    }
  }
}

// ---------------------------------------------------------------------------
// Kernel 2: fused attention. One block = (bh, 64 q-rows). 4 waves, wave w owns
// i-strip [16w,16w+16). S computed TRANSPOSED (A=k,B=q): lane holds
// St[j=16mt+4q+r][i=l15]. Bias GEMMs Qe=q@E^T (per-wave) and Ke=k@E^T (coop)
// store SHEARED [i][j] so the softmax gather is aligned s16x4. Max-free
// online softmax. PV via P through per-wave LDS (aliases Qe region).
// No s_setprio (4-wave lockstep block: scheduler freedom > wave priority).
// ---------------------------------------------------------------------------
__global__ __launch_bounds__(256, 3) void attn_kernel(
    const unsigned short* __restrict__ qb, const unsigned short* __restrict__ kb,
    const unsigned short* __restrict__ vtb, const unsigned short* __restrict__ ebf,
    const float* __restrict__ mask, float* __restrict__ out) {
  __shared__ unsigned short ksw[64 * 64];        // 8KB   swizzled
  __shared__ unsigned short vsw[64 * 64];        // 8KB   swizzled (rows = d)
  __shared__ unsigned short esw[128 * 64];       // 16KB  swizzled (rows = t)
  __shared__ unsigned short keS[64 * 68];        // 8.5KB sheared Ke[i][j], stride 68
  __shared__ unsigned short qp[4][16 * 72];      // 9KB   per-wave sheared Qe[i][j] / P[i][j]
  __shared__ unsigned short mlb[1024];           // 2KB   mask row * log2(e), bf16
  // total 51.5KB -> 3 blocks/CU

  const int tid = threadIdx.x;
  const int w = tid >> 6, lane = tid & 63, quad = lane >> 4, l15 = lane & 15;
  const int blk0 = blockIdx.x;
  const int blk = (blk0 & 7) * 96 + (blk0 >> 3);   // XCD-bijective (768 = 8*96):
  const int bh = blk >> 4;                         // all 16 l-tiles of a bh on one XCD
  const int l0 = (blk & 15) << 6;
  const int b = bh / 12;
  const int h = bh - b * 12;

  const float SC1 = 0.18033688f;   // log2(e)/8
  const float SC2 = 1.44269504f;   // log2(e)

  const unsigned short* kbh = kb + (size_t)bh * 65536;
  const unsigned short* vbh = vtb + (size_t)bh * 65536;
  unsigned short* qpw = &qp[w][0];

  // ---- staging helpers (async global->LDS, 16B/lane, xor-swizzled chunks)
  auto stage_k = [&](int r0) {
    const unsigned short* kbase = kbh + (size_t)r0 * 64;
#pragma unroll
    for (int i = 0; i < 2; ++i) {
      int cl = (w * 2 + i) * 64 + lane;
      int row = cl >> 3, cp = cl & 7, gch = cp ^ (row & 7);
      __builtin_amdgcn_global_load_lds((GCV*)(kbase + row * 64 + gch * 8),
                                       (LDSV*)(ksw + (size_t)(w * 2 + i) * 512), 16, 0, 0);
    }
  };
  auto stage_v = [&](int r0) {
    const unsigned short* vbase = vbh + r0;
#pragma unroll
    for (int i = 0; i < 2; ++i) {
      int cl = (w * 2 + i) * 64 + lane;
      int row = cl >> 3, cp = cl & 7, gch = cp ^ (row & 7);
      __builtin_amdgcn_global_load_lds((GCV*)(vbase + (size_t)row * 1024 + gch * 8),
                                       (LDSV*)(vsw + (size_t)(w * 2 + i) * 512), 16, 0, 0);
    }
  };
  auto stage_e = [&](int dbase) {
    const unsigned short* ebase = ebf + (size_t)dbase * 64;
#pragma unroll
    for (int i = 0; i < 4; ++i) {
      int cl = (w * 4 + i) * 64 + lane;
      int row = cl >> 3, cp = cl & 7, gch = cp ^ (row & 7);
      __builtin_amdgcn_global_load_lds((GCV*)(ebase + row * 64 + gch * 8),
                                       (LDSV*)(esw + (size_t)(w * 4 + i) * 512), 16, 0, 0);
    }
  };

  // stage mask row (pre-scaled by log2e, bf16); ordered by first top barrier
  {
    float4 mv = ((const float4*)(mask + (size_t)b * 1024))[tid];
    ushort4 ms;
    ms.x = f2bf(mv.x * SC2); ms.y = f2bf(mv.y * SC2);
    ms.z = f2bf(mv.z * SC2); ms.w = f2bf(mv.w * SC2);
    *(ushort4*)(mlb + tid * 4) = ms;
  }

  // q B-frags for strip row l0+16w+l15 (held all 16 iters)
  const unsigned short* qrow = qb + (size_t)bh * 65536 + (size_t)(l0 + 16 * w + l15) * 64;
  s16x8 qf[2];
  qf[0] = *(const s16x8*)(qrow + quad * 8);
  qf[1] = *(const s16x8*)(qrow + 32 + quad * 8);

  f32x4 oacc[4];
#pragma unroll
  for (int i = 0; i < 4; ++i) oacc[i] = (f32x4){0.f, 0.f, 0.f, 0.f};
  float lsum = 0.f;

  // ---- prologue: stage k/E for it=0
  stage_k(0);
  stage_e(l0 + 960);

  for (int it = 0; it < 16; ++it) {
    const int r0 = it << 6;
    __syncthreads();   // top: k/E(it) ready (vmcnt drain); all prev-iter PV reads done
    stage_v(r0);       // into single-buffer vsw; latency covered by phase1

    // ---- phase1: k A-frags (feed St and Ke)
    s16x8 kf[4][2];
#pragma unroll
    for (int mt = 0; mt < 4; ++mt)
#pragma unroll
      for (int ks = 0; ks < 2; ++ks) {
        int row = 16 * mt + l15;
        kf[mt][ks] = *(const s16x8*)(ksw + row * 64 + (((quad + 4 * ks) ^ (row & 7)) * 8));
      }

    // ---- St[j][i] = k . q
    f32x4 st[4];
#pragma unroll
    for (int mt = 0; mt < 4; ++mt) {
      f32x4 a = (f32x4){0.f, 0.f, 0.f, 0.f};
      a = MFMA(kf[mt][0], qf[0], a);
      a = MFMA(kf[mt][1], qf[1], a);
      st[mt] = a;
    }

    // ---- Qe (wave window t-tiles [w, w+4]): a[r] is Qe at
    //   (i_local = 4*quad + r, t = 16*(w+tp) + l15);  sheared col
    //   j = i + 63 - t = (4*quad + r) + 63 - 16*tp - l15   (w cancels).
    // Ke piggybacks on tp==w, w+1 (wave-uniform; tiles tt = 2w, 2w+1):
    //   ka[r] is Ke at (t = 16*tt + l15, j = 16*mt + 4*quad + r);
    //   sheared row i = t + j - 63.
#pragma unroll
    for (int tp = 0; tp < 5; ++tp) {
      int tt = w + tp;
      int row = 16 * tt + l15;
      s16x8 ef0 = *(const s16x8*)(esw + row * 64 + ((quad ^ (row & 7)) * 8));
      s16x8 ef1 = *(const s16x8*)(esw + row * 64 + (((quad + 4) ^ (row & 7)) * 8));
      f32x4 a = (f32x4){0.f, 0.f, 0.f, 0.f};
      a = MFMA(qf[0], ef0, a);
      a = MFMA(qf[1], ef1, a);
#pragma unroll
      for (int r = 0; r < 4; ++r) {
        int j = 4 * quad + r + 63 - 16 * tp - l15;
        if ((unsigned)j < 64u) qpw[(4 * quad + r) * 72 + j] = f2bf(a[r]);
      }
      if (tp == w || tp == w + 1) {
#pragma unroll
        for (int mt = 0; mt < 4; ++mt) {
          f32x4 kacc = (f32x4){0.f, 0.f, 0.f, 0.f};
          kacc = MFMA(kf[mt][0], ef0, kacc);
          kacc = MFMA(kf[mt][1], ef1, kacc);
          int jb = 16 * mt + 4 * quad;
          int ib0 = 16 * tt + l15 + jb - 63;
#pragma unroll
          for (int r = 0; r < 4; ++r) {
            int ii = ib0 + r;
            if ((unsigned)ii < 64u) keS[ii * 68 + jb + r] = f2bf(kacc[r]);
          }
        }
      }
    }
    __syncthreads();   // mid: drains vmcnt (vsw ready); keS/qp visible block-wide

    // ---- issue stage k/E for it+1 (drained at next top barrier; phase2
    // below covers the latency)
    if (it < 15) {
      stage_k(r0 + 64);
      stage_e(l0 - r0 - 64 + 960);
    }

    // ---- phase2: softmax — sheared bias rows are plain [i][j]: aligned s16x4
    float pr[4][4];
#pragma unroll
    for (int mt = 0; mt < 4; ++mt) {
      int jb = 16 * mt + 4 * quad;
      s16x4 qv4 = *(const s16x4*)(qpw + l15 * 72 + jb);
      s16x4 kv4 = *(const s16x4*)(keS + (16 * w + l15) * 68 + jb);
      s16x4 mk4 = *(const s16x4*)(mlb + r0 + jb);
#pragma unroll
      for (int r = 0; r < 4; ++r) {
        float bias = bf2f((unsigned short)qv4[r]) + bf2f((unsigned short)kv4[r]);
        float p = exp2f((st[mt][r] + bias) * SC1 + bf2f((unsigned short)mk4[r]));
        pr[mt][r] = p;
        lsum += p;
      }
    }

    // ---- P -> per-wave LDS [i=l15][j] (b64 stores; same cells the thread
    // just read as qv4 -> per-thread RAW order holds), then A-frags
#pragma unroll
    for (int mt = 0; mt < 4; ++mt) {
      uint2 pk; pk.x = packbf(pr[mt][0], pr[mt][1]); pk.y = packbf(pr[mt][2], pr[mt][3]);
      *(uint2*)(qpw + l15 * 72 + 16 * mt + 4 * quad) = pk;
    }
    s16x8 pf0 = *(const s16x8*)(qpw + l15 * 72 + quad * 8);
    s16x8 pf1 = *(const s16x8*)(qpw + l15 * 72 + 32 + quad * 8);

    // ---- O += P @ V  (B-frags from transposed V in LDS)
#pragma unroll
    for (int dt = 0; dt < 4; ++dt) {
      int row = 16 * dt + l15;
      s16x8 vf0 = *(const s16x8*)(vsw + row * 64 + ((quad ^ (row & 7)) * 8));
      s16x8 vf1 = *(const s16x8*)(vsw + row * 64 + (((quad + 4) ^ (row & 7)) * 8));
      oacc[dt] = MFMA(pf0, vf0, oacc[dt]);
      oacc[dt] = MFMA(pf1, vf1, oacc[dt]);
    }
  }

  // ---- finalize: row sums live per-lane (i=l15); combine quads, divide, store
  lsum += __shfl_xor(lsum, 16, 64);
  lsum += __shfl_xor(lsum, 32, 64);
#pragma unroll
  for (int r = 0; r < 4; ++r) {
    float ls = __shfl(lsum, quad * 4 + r, 64);
    float rinv = 1.0f / ls;
    int l = l0 + 16 * w + quad * 4 + r;
    float* dst = out + ((size_t)(b * 1024 + l)) * 768 + h * 64;
#pragma unroll
    for (int dt = 0; dt < 4; ++dt) dst[16 * dt + l15] = oacc[dt][r] * rinv;
  }
}

// ---------------------------------------------------------------------------
extern "C" void kernel_launch(void* const* d_in, const int* in_sizes, int n_in,
                              void* d_out, int out_size, void* d_ws, size_t ws_size,
                              hipStream_t stream) {
  const float* hid  = (const float*)d_in[0];
  const float* mask = (const float*)d_in[1];
  const float* wq   = (const float*)d_in[2];
  const float* bq   = (const float*)d_in[3];
  const float* wk   = (const float*)d_in[4];
  const float* bk   = (const float*)d_in[5];
  const float* wv   = (const float*)d_in[6];
  const float* bv   = (const float*)d_in[7];
  const float* de   = (const float*)d_in[8];

  char* ws = (char*)d_ws;
  unsigned short* hidbf = (unsigned short*)(ws);                  // 6,291,456 B
  unsigned short* wbf   = (unsigned short*)(ws + 6291456);        // 3,538,944 B
  unsigned short* ebf   = (unsigned short*)(ws + 9830400);        //   262,144 B
  unsigned short* qb    = (unsigned short*)(ws + 10092544);       // 6,291,456 B
  unsigned short* kb    = (unsigned short*)(ws + 16384000);       // 6,291,456 B
  unsigned short* vtb   = (unsigned short*)(ws + 22675456);       // 6,291,456 B

  convert_kernel<<<4928, 256, 0, stream>>>(hid, wq, wk, wv, de, hidbf, wbf, ebf);
  qkv_gemm<<<dim3(32, 18), 256, 0, stream>>>(hidbf, wbf, bq, bk, bv, qb, kb, vtb);
  attn_kernel<<<768, 256, 0, stream>>>(qb, kb, vtb, ebf, mask, (float*)d_out);
}

// Round 10
// 180.502 us; speedup vs baseline: 1.0634x; 1.0048x over previous
//
#include <hip/hip_runtime.h>
#include <stdint.h>

// ---------------------------------------------------------------------------
// BertSelfAttention (relative_key_query) on gfx950.
// B=4 S=1024 H=768 nH=12 dH=64 MAXPOS=1024.
//   q,k,v = hidden @ W{q,k,v}.T + b        (bf16 MFMA GEMM)
//   S[l,r] = q.k + q.E[l-r+1023] + k.E[l-r+1023];  softmax(S/8 + mask) @ v
// Pipeline: convert(fp32->bf16) -> qkv_gemm -> fused flash attention.
// v11 = v10 with ONE change: qkv_gemm launch_bounds (256,2) -> (256,3).
//   LDS 32KB x 3 = 96KB fits; reg need ~148 < ~170 budget at 3 waves/SIMD.
//   576 blocks <= 256 CU x 3 => whole grid co-resident, zero tail (was 2.25
//   rounds at 2/CU), and 3-deep wave overlap hides the per-iter vmcnt drains
//   (R8's explicit dbuf traded LDS/occupancy for this and lost; this is the
//   free version).
// ---------------------------------------------------------------------------

typedef __attribute__((ext_vector_type(4))) float f32x4;
typedef __attribute__((ext_vector_type(8))) short s16x8;
typedef __attribute__((ext_vector_type(4))) short s16x4;
typedef const __attribute__((address_space(1))) void GCV;
typedef __attribute__((address_space(3))) void LDSV;

__device__ __forceinline__ unsigned short f2bf(float f) {
  union { float f; uint32_t u; } v; v.f = f;
  uint32_t r = (v.u + 0x7FFFu + ((v.u >> 16) & 1u)) >> 16;
  return (unsigned short)r;
}
__device__ __forceinline__ float bf2f(unsigned short b) {
  union { uint32_t u; float f; } v; v.u = ((uint32_t)b) << 16;
  return v.f;
}
__device__ __forceinline__ uint32_t packbf(float a, float b) {
  return (uint32_t)f2bf(a) | ((uint32_t)f2bf(b) << 16);
}

#define MFMA(a, b, c) __builtin_amdgcn_mfma_f32_16x16x32_bf16((a), (b), (c), 0, 0, 0)

// ---------------------------------------------------------------------------
// Kernel 0: fp32 -> bf16 conversion. hidden [4096x768], Wq|Wk|Wv [768x768]x3,
// dist_emb [2047x64] padded to 2048 rows (row 2047 = 0).
// ---------------------------------------------------------------------------
#define HIDQ 786432   // 4096*768/4
#define WQ4  147456   // 768*768/4
#define EQ4  32768    // 2048*64/4

__global__ __launch_bounds__(256) void convert_kernel(
    const float* __restrict__ hid, const float* __restrict__ wq,
    const float* __restrict__ wk, const float* __restrict__ wv,
    const float* __restrict__ de,
    unsigned short* __restrict__ hidbf, unsigned short* __restrict__ wbf,
    unsigned short* __restrict__ ebf) {
  int g = blockIdx.x * 256 + threadIdx.x;
  if (g < HIDQ) {
    float4 s = ((const float4*)hid)[g];
    ushort4 o; o.x = f2bf(s.x); o.y = f2bf(s.y); o.z = f2bf(s.z); o.w = f2bf(s.w);
    ((ushort4*)hidbf)[g] = o;
  } else if (g < HIDQ + 3 * WQ4) {
    int r = g - HIDQ;
    int sel = r / WQ4, r2 = r - sel * WQ4;
    const float* src = sel == 0 ? wq : (sel == 1 ? wk : wv);
    float4 s = ((const float4*)src)[r2];
    ushort4 o; o.x = f2bf(s.x); o.y = f2bf(s.y); o.z = f2bf(s.z); o.w = f2bf(s.w);
    ((ushort4*)wbf)[r] = o;
  } else {
    int r = g - HIDQ - 3 * WQ4;      // [0, 32768)
    int e = 4 * r;                   // element index into 2048*64
    ushort4 o;
    o.x = (e + 0 < 131008) ? f2bf(de[e + 0]) : 0;
    o.y = (e + 1 < 131008) ? f2bf(de[e + 1]) : 0;
    o.z = (e + 2 < 131008) ? f2bf(de[e + 2]) : 0;
    o.w = (e + 3 < 131008) ? f2bf(de[e + 3]) : 0;
    ((ushort4*)ebf)[r] = o;
  }
}

// ---------------------------------------------------------------------------
// Kernel 1: QKV projection GEMM.  C[m, o] = sum_i hid[m,i] * W[o,i] + bias[o]
// M=4096, N=2304 (q|k|v), K=768. 128x128 tile, BK=64, 4 waves (64x64 each).
// R6 structure; (256,3): 576 blocks all co-resident at 3 blocks/CU.
// Outputs: q,k -> [bh][s][64] bf16 ; v -> transposed [bh][d][1024] bf16.
// ---------------------------------------------------------------------------
__global__ __launch_bounds__(256, 3) void qkv_gemm(
    const unsigned short* __restrict__ hidbf,   // [4096][768]
    const unsigned short* __restrict__ wbf,     // [3][768][768]
    const float* __restrict__ bq, const float* __restrict__ bk,
    const float* __restrict__ bv,
    unsigned short* __restrict__ qb, unsigned short* __restrict__ kb,
    unsigned short* __restrict__ vtb) {
  __shared__ unsigned short lda[128 * 64];   // 16KB, xor-swizzled 16B chunks
  __shared__ unsigned short ldb[128 * 64];   // 16KB
  const int tid = threadIdx.x;
  const int w = tid >> 6, lane = tid & 63, quad = lane >> 4, l15 = lane & 15;
  const int m0 = blockIdx.x * 128;
  const int bn = blockIdx.y;
  const int sel = bn / 6;
  const int nc0 = (bn - sel * 6) * 128;
  const unsigned short* wsrc = wbf + (size_t)sel * 589824;

  f32x4 acc[4][4];
#pragma unroll
  for (int i = 0; i < 4; ++i)
#pragma unroll
    for (int j = 0; j < 4; ++j) acc[i][j] = (f32x4){0.f, 0.f, 0.f, 0.f};

  const int rA = 64 * (w & 1);
  const int rB = 64 * (w >> 1);

  for (int kit = 0; kit < 12; ++kit) {
    int k0 = kit * 64;
    __syncthreads();
    // stage A,B: [128 rows][64 bf16]; chunk-linear = row*8 + cpos, xor swizzle
#pragma unroll
    for (int i = 0; i < 4; ++i) {
      int cl = (w * 4 + i) * 64 + lane;
      int row = cl >> 3, cp = cl & 7, gch = cp ^ (row & 7);
      __builtin_amdgcn_global_load_lds(
          (GCV*)(hidbf + (size_t)(m0 + row) * 768 + k0 + gch * 8),
          (LDSV*)(lda + (size_t)(w * 4 + i) * 512), 16, 0, 0);
      __builtin_amdgcn_global_load_lds(
          (GCV*)(wsrc + (size_t)(nc0 + row) * 768 + k0 + gch * 8),
          (LDSV*)(ldb + (size_t)(w * 4 + i) * 512), 16, 0, 0);
    }
    __syncthreads();

    s16x8 af[4][2], bfr[4][2];
#pragma unroll
    for (int mt = 0; mt < 4; ++mt)
#pragma unroll
      for (int ks = 0; ks < 2; ++ks) {
        int row = rA + 16 * mt + l15;
        af[mt][ks] = *(const s16x8*)(lda + row * 64 + (((quad + 4 * ks) ^ (row & 7)) * 8));
        int rowb = rB + 16 * mt + l15;
        bfr[mt][ks] = *(const s16x8*)(ldb + rowb * 64 + (((quad + 4 * ks) ^ (rowb & 7)) * 8));
      }
#pragma unroll
    for (int mt = 0; mt < 4; ++mt)
#pragma unroll
      for (int nt = 0; nt < 4; ++nt) {
        acc[mt][nt] = MFMA(af[mt][0], bfr[nt][0], acc[mt][nt]);
        acc[mt][nt] = MFMA(af[mt][1], bfr[nt][1], acc[mt][nt]);
      }
  }

  const float* bias = sel == 0 ? bq : (sel == 1 ? bk : bv);
#pragma unroll
  for (int nt = 0; nt < 4; ++nt) {
    int oc = nc0 + rB + 16 * nt + l15;          // [0,768)
    float bvl = bias[oc];
    int h = oc >> 6, dd = oc & 63;
#pragma unroll
    for (int mt = 0; mt < 4; ++mt) {
      int mbase = m0 + rA + 16 * mt + quad * 4;
      int b = mbase >> 10, s = mbase & 1023;
      size_t bh = (size_t)(b * 12 + h);
      if (sel < 2) {
        unsigned short* dst = (sel == 0 ? qb : kb) + bh * 65536 + (size_t)s * 64 + dd;
#pragma unroll
        for (int r = 0; r < 4; ++r) dst[(size_t)r * 64] = f2bf(acc[mt][nt][r] + bvl);
      } else {
        ushort4 pk;
        pk.x = f2bf(acc[mt][nt][0] + bvl); pk.y = f2bf(acc[mt][nt][1] + bvl);
        pk.z = f2bf(acc[mt][nt][2] + bvl); pk.w = f2bf(acc[mt][nt][3] + bvl);
        *(ushort4*)(vtb + bh * 65536 + (size_t)dd * 1024 + s) = pk;
      }
    }
  }
}

// ---------------------------------------------------------------------------
// Kernel 2: fused attention. One block = (bh, 64 q-rows). 4 waves, wave w owns
// i-strip [16w,16w+16). S computed TRANSPOSED (A=k,B=q): lane holds
// St[j=16mt+4q+r][i=l15]. Bias GEMMs Qe=q@E^T (per-wave) and Ke=k@E^T (coop)
// store SHEARED [i][j] so the softmax gather is aligned s16x4. Max-free
// online softmax. PV via P through per-wave LDS (aliases Qe region).
// No s_setprio (4-wave lockstep block: scheduler freedom > wave priority).
// ---------------------------------------------------------------------------
__global__ __launch_bounds__(256, 3) void attn_kernel(
    const unsigned short* __restrict__ qb, const unsigned short* __restrict__ kb,
    const unsigned short* __restrict__ vtb, const unsigned short* __restrict__ ebf,
    const float* __restrict__ mask, float* __restrict__ out) {
  __shared__ unsigned short ksw[64 * 64];        // 8KB   swizzled
  __shared__ unsigned short vsw[64 * 64];        // 8KB   swizzled (rows = d)
  __shared__ unsigned short esw[128 * 64];       // 16KB  swizzled (rows = t)
  __shared__ unsigned short keS[64 * 68];        // 8.5KB sheared Ke[i][j], stride 68
  __shared__ unsigned short qp[4][16 * 72];      // 9KB   per-wave sheared Qe[i][j] / P[i][j]
  __shared__ unsigned short mlb[1024];           // 2KB   mask row * log2(e), bf16
  // total 51.5KB -> 3 blocks/CU

  const int tid = threadIdx.x;
  const int w = tid >> 6, lane = tid & 63, quad = lane >> 4, l15 = lane & 15;
  const int blk0 = blockIdx.x;
  const int blk = (blk0 & 7) * 96 + (blk0 >> 3);   // XCD-bijective (768 = 8*96):
  const int bh = blk >> 4;                         // all 16 l-tiles of a bh on one XCD
  const int l0 = (blk & 15) << 6;
  const int b = bh / 12;
  const int h = bh - b * 12;

  const float SC1 = 0.18033688f;   // log2(e)/8
  const float SC2 = 1.44269504f;   // log2(e)

  const unsigned short* kbh = kb + (size_t)bh * 65536;
  const unsigned short* vbh = vtb + (size_t)bh * 65536;
  unsigned short* qpw = &qp[w][0];

  // ---- staging helpers (async global->LDS, 16B/lane, xor-swizzled chunks)
  auto stage_k = [&](int r0) {
    const unsigned short* kbase = kbh + (size_t)r0 * 64;
#pragma unroll
    for (int i = 0; i < 2; ++i) {
      int cl = (w * 2 + i) * 64 + lane;
      int row = cl >> 3, cp = cl & 7, gch = cp ^ (row & 7);
      __builtin_amdgcn_global_load_lds((GCV*)(kbase + row * 64 + gch * 8),
                                       (LDSV*)(ksw + (size_t)(w * 2 + i) * 512), 16, 0, 0);
    }
  };
  auto stage_v = [&](int r0) {
    const unsigned short* vbase = vbh + r0;
#pragma unroll
    for (int i = 0; i < 2; ++i) {
      int cl = (w * 2 + i) * 64 + lane;
      int row = cl >> 3, cp = cl & 7, gch = cp ^ (row & 7);
      __builtin_amdgcn_global_load_lds((GCV*)(vbase + (size_t)row * 1024 + gch * 8),
                                       (LDSV*)(vsw + (size_t)(w * 2 + i) * 512), 16, 0, 0);
    }
  };
  auto stage_e = [&](int dbase) {
    const unsigned short* ebase = ebf + (size_t)dbase * 64;
#pragma unroll
    for (int i = 0; i < 4; ++i) {
      int cl = (w * 4 + i) * 64 + lane;
      int row = cl >> 3, cp = cl & 7, gch = cp ^ (row & 7);
      __builtin_amdgcn_global_load_lds((GCV*)(ebase + row * 64 + gch * 8),
                                       (LDSV*)(esw + (size_t)(w * 4 + i) * 512), 16, 0, 0);
    }
  };

  // stage mask row (pre-scaled by log2e, bf16); ordered by first top barrier
  {
    float4 mv = ((const float4*)(mask + (size_t)b * 1024))[tid];
    ushort4 ms;
    ms.x = f2bf(mv.x * SC2); ms.y = f2bf(mv.y * SC2);
    ms.z = f2bf(mv.z * SC2); ms.w = f2bf(mv.w * SC2);
    *(ushort4*)(mlb + tid * 4) = ms;
  }

  // q B-frags for strip row l0+16w+l15 (held all 16 iters)
  const unsigned short* qrow = qb + (size_t)bh * 65536 + (size_t)(l0 + 16 * w + l15) * 64;
  s16x8 qf[2];
  qf[0] = *(const s16x8*)(qrow + quad * 8);
  qf[1] = *(const s16x8*)(qrow + 32 + quad * 8);

  f32x4 oacc[4];
#pragma unroll
  for (int i = 0; i < 4; ++i) oacc[i] = (f32x4){0.f, 0.f, 0.f, 0.f};
  float lsum = 0.f;

  // ---- prologue: stage k/E for it=0
  stage_k(0);
  stage_e(l0 + 960);

  for (int it = 0; it < 16; ++it) {
    const int r0 = it << 6;
    __syncthreads();   // top: k/E(it) ready (vmcnt drain); all prev-iter PV reads done
    stage_v(r0);       // into single-buffer vsw; latency covered by phase1

    // ---- phase1: k A-frags (feed St and Ke)
    s16x8 kf[4][2];
#pragma unroll
    for (int mt = 0; mt < 4; ++mt)
#pragma unroll
      for (int ks = 0; ks < 2; ++ks) {
        int row = 16 * mt + l15;
        kf[mt][ks] = *(const s16x8*)(ksw + row * 64 + (((quad + 4 * ks) ^ (row & 7)) * 8));
      }

    // ---- St[j][i] = k . q
    f32x4 st[4];
#pragma unroll
    for (int mt = 0; mt < 4; ++mt) {
      f32x4 a = (f32x4){0.f, 0.f, 0.f, 0.f};
      a = MFMA(kf[mt][0], qf[0], a);
      a = MFMA(kf[mt][1], qf[1], a);
      st[mt] = a;
    }

    // ---- Qe (wave window t-tiles [w, w+4]): a[r] is Qe at
    //   (i_local = 4*quad + r, t = 16*(w+tp) + l15);  sheared col
    //   j = i + 63 - t = (4*quad + r) + 63 - 16*tp - l15   (w cancels).
    // Ke piggybacks on tp==w, w+1 (wave-uniform; tiles tt = 2w, 2w+1):
    //   ka[r] is Ke at (t = 16*tt + l15, j = 16*mt + 4*quad + r);
    //   sheared row i = t + j - 63.
#pragma unroll
    for (int tp = 0; tp < 5; ++tp) {
      int tt = w + tp;
      int row = 16 * tt + l15;
      s16x8 ef0 = *(const s16x8*)(esw + row * 64 + ((quad ^ (row & 7)) * 8));
      s16x8 ef1 = *(const s16x8*)(esw + row * 64 + (((quad + 4) ^ (row & 7)) * 8));
      f32x4 a = (f32x4){0.f, 0.f, 0.f, 0.f};
      a = MFMA(qf[0], ef0, a);
      a = MFMA(qf[1], ef1, a);
#pragma unroll
      for (int r = 0; r < 4; ++r) {
        int j = 4 * quad + r + 63 - 16 * tp - l15;
        if ((unsigned)j < 64u) qpw[(4 * quad + r) * 72 + j] = f2bf(a[r]);
      }
      if (tp == w || tp == w + 1) {
#pragma unroll
        for (int mt = 0; mt < 4; ++mt) {
          f32x4 kacc = (f32x4){0.f, 0.f, 0.f, 0.f};
          kacc = MFMA(kf[mt][0], ef0, kacc);
          kacc = MFMA(kf[mt][1], ef1, kacc);
          int jb = 16 * mt + 4 * quad;
          int ib0 = 16 * tt + l15 + jb - 63;
#pragma unroll
          for (int r = 0; r < 4; ++r) {
            int ii = ib0 + r;
            if ((unsigned)ii < 64u) keS[ii * 68 + jb + r] = f2bf(kacc[r]);
          }
        }
      }
    }
    __syncthreads();   // mid: drains vmcnt (vsw ready); keS/qp visible block-wide

    // ---- issue stage k/E for it+1 (drained at next top barrier; phase2
    // below covers the latency)
    if (it < 15) {
      stage_k(r0 + 64);
      stage_e(l0 - r0 - 64 + 960);
    }

    // ---- phase2: softmax — sheared bias rows are plain [i][j]: aligned s16x4
    float pr[4][4];
#pragma unroll
    for (int mt = 0; mt < 4; ++mt) {
      int jb = 16 * mt + 4 * quad;
      s16x4 qv4 = *(const s16x4*)(qpw + l15 * 72 + jb);
      s16x4 kv4 = *(const s16x4*)(keS + (16 * w + l15) * 68 + jb);
      s16x4 mk4 = *(const s16x4*)(mlb + r0 + jb);
#pragma unroll
      for (int r = 0; r < 4; ++r) {
        float bias = bf2f((unsigned short)qv4[r]) + bf2f((unsigned short)kv4[r]);
        float p = exp2f((st[mt][r] + bias) * SC1 + bf2f((unsigned short)mk4[r]));
        pr[mt][r] = p;
        lsum += p;
      }
    }

    // ---- P -> per-wave LDS [i=l15][j] (b64 stores; same cells the thread
    // just read as qv4 -> per-thread RAW order holds), then A-frags
#pragma unroll
    for (int mt = 0; mt < 4; ++mt) {
      uint2 pk; pk.x = packbf(pr[mt][0], pr[mt][1]); pk.y = packbf(pr[mt][2], pr[mt][3]);
      *(uint2*)(qpw + l15 * 72 + 16 * mt + 4 * quad) = pk;
    }
    s16x8 pf0 = *(const s16x8*)(qpw + l15 * 72 + quad * 8);
    s16x8 pf1 = *(const s16x8*)(qpw + l15 * 72 + 32 + quad * 8);

    // ---- O += P @ V  (B-frags from transposed V in LDS)
#pragma unroll
    for (int dt = 0; dt < 4; ++dt) {
      int row = 16 * dt + l15;
      s16x8 vf0 = *(const s16x8*)(vsw + row * 64 + ((quad ^ (row & 7)) * 8));
      s16x8 vf1 = *(const s16x8*)(vsw + row * 64 + (((quad + 4) ^ (row & 7)) * 8));
      oacc[dt] = MFMA(pf0, vf0, oacc[dt]);
      oacc[dt] = MFMA(pf1, vf1, oacc[dt]);
    }
  }

  // ---- finalize: row sums live per-lane (i=l15); combine quads, divide, store
  lsum += __shfl_xor(lsum, 16, 64);
  lsum += __shfl_xor(lsum, 32, 64);
#pragma unroll
  for (int r = 0; r < 4; ++r) {
    float ls = __shfl(lsum, quad * 4 + r, 64);
    float rinv = 1.0f / ls;
    int l = l0 + 16 * w + quad * 4 + r;
    float* dst = out + ((size_t)(b * 1024 + l)) * 768 + h * 64;
#pragma unroll
    for (int dt = 0; dt < 4; ++dt) dst[16 * dt + l15] = oacc[dt][r] * rinv;
  }
}

// ---------------------------------------------------------------------------
extern "C" void kernel_launch(void* const* d_in, const int* in_sizes, int n_in,
                              void* d_out, int out_size, void* d_ws, size_t ws_size,
                              hipStream_t stream) {
  const float* hid  = (const float*)d_in[0];
  const float* mask = (const float*)d_in[1];
  const float* wq   = (const float*)d_in[2];
  const float* bq   = (const float*)d_in[3];
  const float* wk   = (const float*)d_in[4];
  const float* bk   = (const float*)d_in[5];
  const float* wv   = (const float*)d_in[6];
  const float* bv   = (const float*)d_in[7];
  const float* de   = (const float*)d_in[8];

  char* ws = (char*)d_ws;
  unsigned short* hidbf = (unsigned short*)(ws);                  // 6,291,456 B
  unsigned short* wbf   = (unsigned short*)(ws + 6291456);        // 3,538,944 B
  unsigned short* ebf   = (unsigned short*)(ws + 9830400);        //   262,144 B
  unsigned short* qb    = (unsigned short*)(ws + 10092544);       // 6,291,456 B
  unsigned short* kb    = (unsigned short*)(ws + 16384000);       // 6,291,456 B
  unsigned short* vtb   = (unsigned short*)(ws + 22675456);       // 6,291,456 B

  convert_kernel<<<4928, 256, 0, stream>>>(hid, wq, wk, wv, de, hidbf, wbf, ebf);
  qkv_gemm<<<dim3(32, 18), 256, 0, stream>>>(hidbf, wbf, bq, bk, bv, qb, kb, vtb);
  attn_kernel<<<768, 256, 0, stream>>>(qb, kb, vtb, ebf, mask, (float*)d_out);
}

// Round 12
// 173.362 us; speedup vs baseline: 1.1072x; 1.0412x over previous
//
#include <hip/hip_runtime.h>
#include <stdint.h>

// ---------------------------------------------------------------------------
// BertSelfAttention (relative_key_query) on gfx950.
// B=4 S=1024 H=768 nH=12 dH=64 MAXPOS=1024.
//   q,k,v = hidden @ W{q,k,v}.T + b        (bf16 MFMA GEMM)
//   S[l,r] = q.k + q.E[l-r+1023] + k.E[l-r+1023];  softmax(S/8 + mask) @ v
// Pipeline: convert(fp32->bf16) -> qkv_gemm -> fused flash attention.
// v13 = v12 minus cvtpk (NaN evidence: R1+R11 failed with cvtpk, R6 passed
// without; m240 says hand-written cvt_pk is slower than scalar casts anyway).
// Ke band-cull KEPT (math re-verified: tile (tt,mt) live iff 3<=tt+mt<=7;
// ownership {w, w+4} covers tt 0..7; 5 kept mt-loops/wave, balanced;
// keS contents identical to v10's — old code's predicates killed the same
// dead tiles, just after computing them).
// ---------------------------------------------------------------------------

typedef __attribute__((ext_vector_type(4))) float f32x4;
typedef __attribute__((ext_vector_type(8))) short s16x8;
typedef __attribute__((ext_vector_type(4))) short s16x4;
typedef const __attribute__((address_space(1))) void GCV;
typedef __attribute__((address_space(3))) void LDSV;

__device__ __forceinline__ unsigned short f2bf(float f) {
  union { float f; uint32_t u; } v; v.f = f;
  uint32_t r = (v.u + 0x7FFFu + ((v.u >> 16) & 1u)) >> 16;
  return (unsigned short)r;
}
__device__ __forceinline__ float bf2f(unsigned short b) {
  union { uint32_t u; float f; } v; v.u = ((uint32_t)b) << 16;
  return v.f;
}
__device__ __forceinline__ uint32_t packbf(float a, float b) {
  return (uint32_t)f2bf(a) | ((uint32_t)f2bf(b) << 16);
}

#define MFMA(a, b, c) __builtin_amdgcn_mfma_f32_16x16x32_bf16((a), (b), (c), 0, 0, 0)

// ---------------------------------------------------------------------------
// Kernel 0: fp32 -> bf16 conversion. hidden [4096x768], Wq|Wk|Wv [768x768]x3,
// dist_emb [2047x64] padded to 2048 rows (row 2047 = 0).
// ---------------------------------------------------------------------------
#define HIDQ 786432   // 4096*768/4
#define WQ4  147456   // 768*768/4
#define EQ4  32768    // 2048*64/4

__global__ __launch_bounds__(256) void convert_kernel(
    const float* __restrict__ hid, const float* __restrict__ wq,
    const float* __restrict__ wk, const float* __restrict__ wv,
    const float* __restrict__ de,
    unsigned short* __restrict__ hidbf, unsigned short* __restrict__ wbf,
    unsigned short* __restrict__ ebf) {
  int g = blockIdx.x * 256 + threadIdx.x;
  if (g < HIDQ) {
    float4 s = ((const float4*)hid)[g];
    ushort4 o; o.x = f2bf(s.x); o.y = f2bf(s.y); o.z = f2bf(s.z); o.w = f2bf(s.w);
    ((ushort4*)hidbf)[g] = o;
  } else if (g < HIDQ + 3 * WQ4) {
    int r = g - HIDQ;
    int sel = r / WQ4, r2 = r - sel * WQ4;
    const float* src = sel == 0 ? wq : (sel == 1 ? wk : wv);
    float4 s = ((const float4*)src)[r2];
    ushort4 o; o.x = f2bf(s.x); o.y = f2bf(s.y); o.z = f2bf(s.z); o.w = f2bf(s.w);
    ((ushort4*)wbf)[r] = o;
  } else {
    int r = g - HIDQ - 3 * WQ4;      // [0, 32768)
    int e = 4 * r;                   // element index into 2048*64
    ushort4 o;
    o.x = (e + 0 < 131008) ? f2bf(de[e + 0]) : 0;
    o.y = (e + 1 < 131008) ? f2bf(de[e + 1]) : 0;
    o.z = (e + 2 < 131008) ? f2bf(de[e + 2]) : 0;
    o.w = (e + 3 < 131008) ? f2bf(de[e + 3]) : 0;
    ((ushort4*)ebf)[r] = o;
  }
}

// ---------------------------------------------------------------------------
// Kernel 1: QKV projection GEMM.  C[m, o] = sum_i hid[m,i] * W[o,i] + bias[o]
// M=4096, N=2304 (q|k|v), K=768. 128x128 tile, BK=64, 4 waves (64x64 each).
// R6 structure; (256,3): 576 blocks all co-resident at 3 blocks/CU.
// Outputs: q,k -> [bh][s][64] bf16 ; v -> transposed [bh][d][1024] bf16.
// ---------------------------------------------------------------------------
__global__ __launch_bounds__(256, 3) void qkv_gemm(
    const unsigned short* __restrict__ hidbf,   // [4096][768]
    const unsigned short* __restrict__ wbf,     // [3][768][768]
    const float* __restrict__ bq, const float* __restrict__ bk,
    const float* __restrict__ bv,
    unsigned short* __restrict__ qb, unsigned short* __restrict__ kb,
    unsigned short* __restrict__ vtb) {
  __shared__ unsigned short lda[128 * 64];   // 16KB, xor-swizzled 16B chunks
  __shared__ unsigned short ldb[128 * 64];   // 16KB
  const int tid = threadIdx.x;
  const int w = tid >> 6, lane = tid & 63, quad = lane >> 4, l15 = lane & 15;
  const int m0 = blockIdx.x * 128;
  const int bn = blockIdx.y;
  const int sel = bn / 6;
  const int nc0 = (bn - sel * 6) * 128;
  const unsigned short* wsrc = wbf + (size_t)sel * 589824;

  f32x4 acc[4][4];
#pragma unroll
  for (int i = 0; i < 4; ++i)
#pragma unroll
    for (int j = 0; j < 4; ++j) acc[i][j] = (f32x4){0.f, 0.f, 0.f, 0.f};

  const int rA = 64 * (w & 1);
  const int rB = 64 * (w >> 1);

  for (int kit = 0; kit < 12; ++kit) {
    int k0 = kit * 64;
    __syncthreads();
    // stage A,B: [128 rows][64 bf16]; chunk-linear = row*8 + cpos, xor swizzle
#pragma unroll
    for (int i = 0; i < 4; ++i) {
      int cl = (w * 4 + i) * 64 + lane;
      int row = cl >> 3, cp = cl & 7, gch = cp ^ (row & 7);
      __builtin_amdgcn_global_load_lds(
          (GCV*)(hidbf + (size_t)(m0 + row) * 768 + k0 + gch * 8),
          (LDSV*)(lda + (size_t)(w * 4 + i) * 512), 16, 0, 0);
      __builtin_amdgcn_global_load_lds(
          (GCV*)(wsrc + (size_t)(nc0 + row) * 768 + k0 + gch * 8),
          (LDSV*)(ldb + (size_t)(w * 4 + i) * 512), 16, 0, 0);
    }
    __syncthreads();

    s16x8 af[4][2], bfr[4][2];
#pragma unroll
    for (int mt = 0; mt < 4; ++mt)
#pragma unroll
      for (int ks = 0; ks < 2; ++ks) {
        int row = rA + 16 * mt + l15;
        af[mt][ks] = *(const s16x8*)(lda + row * 64 + (((quad + 4 * ks) ^ (row & 7)) * 8));
        int rowb = rB + 16 * mt + l15;
        bfr[mt][ks] = *(const s16x8*)(ldb + rowb * 64 + (((quad + 4 * ks) ^ (rowb & 7)) * 8));
      }
#pragma unroll
    for (int mt = 0; mt < 4; ++mt)
#pragma unroll
      for (int nt = 0; nt < 4; ++nt) {
        acc[mt][nt] = MFMA(af[mt][0], bfr[nt][0], acc[mt][nt]);
        acc[mt][nt] = MFMA(af[mt][1], bfr[nt][1], acc[mt][nt]);
      }
  }

  const float* bias = sel == 0 ? bq : (sel == 1 ? bk : bv);
#pragma unroll
  for (int nt = 0; nt < 4; ++nt) {
    int oc = nc0 + rB + 16 * nt + l15;          // [0,768)
    float bvl = bias[oc];
    int h = oc >> 6, dd = oc & 63;
#pragma unroll
    for (int mt = 0; mt < 4; ++mt) {
      int mbase = m0 + rA + 16 * mt + quad * 4;
      int b = mbase >> 10, s = mbase & 1023;
      size_t bh = (size_t)(b * 12 + h);
      if (sel < 2) {
        unsigned short* dst = (sel == 0 ? qb : kb) + bh * 65536 + (size_t)s * 64 + dd;
#pragma unroll
        for (int r = 0; r < 4; ++r) dst[(size_t)r * 64] = f2bf(acc[mt][nt][r] + bvl);
      } else {
        ushort4 pk;
        pk.x = f2bf(acc[mt][nt][0] + bvl); pk.y = f2bf(acc[mt][nt][1] + bvl);
        pk.z = f2bf(acc[mt][nt][2] + bvl); pk.w = f2bf(acc[mt][nt][3] + bvl);
        *(ushort4*)(vtb + bh * 65536 + (size_t)dd * 1024 + s) = pk;
      }
    }
  }
}

// ---------------------------------------------------------------------------
// Kernel 2: fused attention. One block = (bh, 64 q-rows). 4 waves, wave w owns
// i-strip [16w,16w+16). S computed TRANSPOSED (A=k,B=q): lane holds
// St[j=16mt+4q+r][i=l15]. Bias GEMMs Qe=q@E^T (per-wave) and Ke=k@E^T (coop,
// band-culled, balanced ownership {w, w+4}) store SHEARED [i][j] so the
// softmax gather is aligned s16x4. Max-free online softmax. PV via P through
// per-wave LDS (aliases Qe region). Manual f2bf packing (cvtpk banned: NaN).
// ---------------------------------------------------------------------------
__global__ __launch_bounds__(256, 3) void attn_kernel(
    const unsigned short* __restrict__ qb, const unsigned short* __restrict__ kb,
    const unsigned short* __restrict__ vtb, const unsigned short* __restrict__ ebf,
    const float* __restrict__ mask, float* __restrict__ out) {
  __shared__ unsigned short ksw[64 * 64];        // 8KB   swizzled
  __shared__ unsigned short vsw[64 * 64];        // 8KB   swizzled (rows = d)
  __shared__ unsigned short esw[128 * 64];       // 16KB  swizzled (rows = t)
  __shared__ unsigned short keS[64 * 68];        // 8.5KB sheared Ke[i][j], stride 68
  __shared__ unsigned short qp[4][16 * 72];      // 9KB   per-wave sheared Qe[i][j] / P[i][j]
  __shared__ unsigned short mlb[1024];           // 2KB   mask row * log2(e), bf16
  // total 51.5KB -> 3 blocks/CU

  const int tid = threadIdx.x;
  const int w = tid >> 6, lane = tid & 63, quad = lane >> 4, l15 = lane & 15;
  const int blk0 = blockIdx.x;
  const int blk = (blk0 & 7) * 96 + (blk0 >> 3);   // XCD-bijective (768 = 8*96):
  const int bh = blk >> 4;                         // all 16 l-tiles of a bh on one XCD
  const int l0 = (blk & 15) << 6;
  const int b = bh / 12;
  const int h = bh - b * 12;

  const float SC1 = 0.18033688f;   // log2(e)/8
  const float SC2 = 1.44269504f;   // log2(e)

  const unsigned short* kbh = kb + (size_t)bh * 65536;
  const unsigned short* vbh = vtb + (size_t)bh * 65536;
  unsigned short* qpw = &qp[w][0];

  // ---- staging helpers (async global->LDS, 16B/lane, xor-swizzled chunks)
  auto stage_k = [&](int r0) {
    const unsigned short* kbase = kbh + (size_t)r0 * 64;
#pragma unroll
    for (int i = 0; i < 2; ++i) {
      int cl = (w * 2 + i) * 64 + lane;
      int row = cl >> 3, cp = cl & 7, gch = cp ^ (row & 7);
      __builtin_amdgcn_global_load_lds((GCV*)(kbase + row * 64 + gch * 8),
                                       (LDSV*)(ksw + (size_t)(w * 2 + i) * 512), 16, 0, 0);
    }
  };
  auto stage_v = [&](int r0) {
    const unsigned short* vbase = vbh + r0;
#pragma unroll
    for (int i = 0; i < 2; ++i) {
      int cl = (w * 2 + i) * 64 + lane;
      int row = cl >> 3, cp = cl & 7, gch = cp ^ (row & 7);
      __builtin_amdgcn_global_load_lds((GCV*)(vbase + (size_t)row * 1024 + gch * 8),
                                       (LDSV*)(vsw + (size_t)(w * 2 + i) * 512), 16, 0, 0);
    }
  };
  auto stage_e = [&](int dbase) {
    const unsigned short* ebase = ebf + (size_t)dbase * 64;
#pragma unroll
    for (int i = 0; i < 4; ++i) {
      int cl = (w * 4 + i) * 64 + lane;
      int row = cl >> 3, cp = cl & 7, gch = cp ^ (row & 7);
      __builtin_amdgcn_global_load_lds((GCV*)(ebase + row * 64 + gch * 8),
                                       (LDSV*)(esw + (size_t)(w * 4 + i) * 512), 16, 0, 0);
    }
  };

  // stage mask row (pre-scaled by log2e, bf16); ordered by first top barrier
  {
    float4 mv = ((const float4*)(mask + (size_t)b * 1024))[tid];
    ushort4 ms;
    ms.x = f2bf(mv.x * SC2); ms.y = f2bf(mv.y * SC2);
    ms.z = f2bf(mv.z * SC2); ms.w = f2bf(mv.w * SC2);
    *(ushort4*)(mlb + tid * 4) = ms;
  }

  // q B-frags for strip row l0+16w+l15 (held all 16 iters)
  const unsigned short* qrow = qb + (size_t)bh * 65536 + (size_t)(l0 + 16 * w + l15) * 64;
  s16x8 qf[2];
  qf[0] = *(const s16x8*)(qrow + quad * 8);
  qf[1] = *(const s16x8*)(qrow + 32 + quad * 8);

  f32x4 oacc[4];
#pragma unroll
  for (int i = 0; i < 4; ++i) oacc[i] = (f32x4){0.f, 0.f, 0.f, 0.f};
  float lsum = 0.f;

  // ---- prologue: stage k/E for it=0
  stage_k(0);
  stage_e(l0 + 960);

  for (int it = 0; it < 16; ++it) {
    const int r0 = it << 6;
    __syncthreads();   // top: k/E(it) ready (vmcnt drain); all prev-iter PV reads done
    stage_v(r0);       // into single-buffer vsw; latency covered by phase1

    // ---- phase1: k A-frags (feed St and Ke)
    s16x8 kf[4][2];
#pragma unroll
    for (int mt = 0; mt < 4; ++mt)
#pragma unroll
      for (int ks = 0; ks < 2; ++ks) {
        int row = 16 * mt + l15;
        kf[mt][ks] = *(const s16x8*)(ksw + row * 64 + (((quad + 4 * ks) ^ (row & 7)) * 8));
      }

    // ---- St[j][i] = k . q
    f32x4 st[4];
#pragma unroll
    for (int mt = 0; mt < 4; ++mt) {
      f32x4 a = (f32x4){0.f, 0.f, 0.f, 0.f};
      a = MFMA(kf[mt][0], qf[0], a);
      a = MFMA(kf[mt][1], qf[1], a);
      st[mt] = a;
    }

    // ---- Qe (wave window t-tiles [w, w+4]): a[r] is Qe at
    //   (i_local = 4*quad + r, t = 16*(w+tp) + l15);  sheared col
    //   j = i + 63 - t = (4*quad + r) + 63 - 16*tp - l15   (w cancels).
    // Ke ownership: wave w owns t-tiles {w, w+4} (tp==0, tp==4) — balanced
    //   5 kept mt-loops/wave after band cull (3 <= tt+mt <= 7; computed
    //   i-range is 16(tt+mt)-63+[0,30], valid i in [0,64)).
#pragma unroll
    for (int tp = 0; tp < 5; ++tp) {
      int tt = w + tp;
      int row = 16 * tt + l15;
      s16x8 ef0 = *(const s16x8*)(esw + row * 64 + ((quad ^ (row & 7)) * 8));
      s16x8 ef1 = *(const s16x8*)(esw + row * 64 + (((quad + 4) ^ (row & 7)) * 8));
      f32x4 a = (f32x4){0.f, 0.f, 0.f, 0.f};
      a = MFMA(qf[0], ef0, a);
      a = MFMA(qf[1], ef1, a);
#pragma unroll
      for (int r = 0; r < 4; ++r) {
        int j = 4 * quad + r + 63 - 16 * tp - l15;
        if ((unsigned)j < 64u) qpw[(4 * quad + r) * 72 + j] = f2bf(a[r]);
      }
      if (tp == 0 || tp == 4) {   // this wave owns Ke t-tiles w, w+4
#pragma unroll
        for (int mt = 0; mt < 4; ++mt) {
          if (mt + tt >= 3 && mt + tt <= 7) {   // band cull (wave-uniform)
            f32x4 kacc = (f32x4){0.f, 0.f, 0.f, 0.f};
            kacc = MFMA(kf[mt][0], ef0, kacc);
            kacc = MFMA(kf[mt][1], ef1, kacc);
            int jb = 16 * mt + 4 * quad;
            int ib0 = 16 * tt + l15 + jb - 63;
#pragma unroll
            for (int r = 0; r < 4; ++r) {
              int ii = ib0 + r;
              if ((unsigned)ii < 64u) keS[ii * 68 + jb + r] = f2bf(kacc[r]);
            }
          }
        }
      }
    }
    __syncthreads();   // mid: drains vmcnt (vsw ready); keS/qp visible block-wide

    // ---- issue stage k/E for it+1 (drained at next top barrier; phase2
    // below covers the latency)
    if (it < 15) {
      stage_k(r0 + 64);
      stage_e(l0 - r0 - 64 + 960);
    }

    // ---- phase2: softmax — sheared bias rows are plain [i][j]: aligned s16x4
    float pr[4][4];
#pragma unroll
    for (int mt = 0; mt < 4; ++mt) {
      int jb = 16 * mt + 4 * quad;
      s16x4 qv4 = *(const s16x4*)(qpw + l15 * 72 + jb);
      s16x4 kv4 = *(const s16x4*)(keS + (16 * w + l15) * 68 + jb);
      s16x4 mk4 = *(const s16x4*)(mlb + r0 + jb);
#pragma unroll
      for (int r = 0; r < 4; ++r) {
        float bias = bf2f((unsigned short)qv4[r]) + bf2f((unsigned short)kv4[r]);
        float p = exp2f((st[mt][r] + bias) * SC1 + bf2f((unsigned short)mk4[r]));
        pr[mt][r] = p;
        lsum += p;
      }
    }

    // ---- P -> per-wave LDS [i=l15][j] (b64 stores; same cells the thread
    // just read as qv4 -> per-thread RAW order holds), then A-frags
#pragma unroll
    for (int mt = 0; mt < 4; ++mt) {
      uint2 pk; pk.x = packbf(pr[mt][0], pr[mt][1]); pk.y = packbf(pr[mt][2], pr[mt][3]);
      *(uint2*)(qpw + l15 * 72 + 16 * mt + 4 * quad) = pk;
    }
    s16x8 pf0 = *(const s16x8*)(qpw + l15 * 72 + quad * 8);
    s16x8 pf1 = *(const s16x8*)(qpw + l15 * 72 + 32 + quad * 8);

    // ---- O += P @ V  (B-frags from transposed V in LDS)
#pragma unroll
    for (int dt = 0; dt < 4; ++dt) {
      int row = 16 * dt + l15;
      s16x8 vf0 = *(const s16x8*)(vsw + row * 64 + ((quad ^ (row & 7)) * 8));
      s16x8 vf1 = *(const s16x8*)(vsw + row * 64 + (((quad + 4) ^ (row & 7)) * 8));
      oacc[dt] = MFMA(pf0, vf0, oacc[dt]);
      oacc[dt] = MFMA(pf1, vf1, oacc[dt]);
    }
  }

  // ---- finalize: row sums live per-lane (i=l15); combine quads, divide, store
  lsum += __shfl_xor(lsum, 16, 64);
  lsum += __shfl_xor(lsum, 32, 64);
#pragma unroll
  for (int r = 0; r < 4; ++r) {
    float ls = __shfl(lsum, quad * 4 + r, 64);
    float rinv = 1.0f / ls;
    int l = l0 + 16 * w + quad * 4 + r;
    float* dst = out + ((size_t)(b * 1024 + l)) * 768 + h * 64;
#pragma unroll
    for (int dt = 0; dt < 4; ++dt) dst[16 * dt + l15] = oacc[dt][r] * rinv;
  }
}

// ---------------------------------------------------------------------------
extern "C" void kernel_launch(void* const* d_in, const int* in_sizes, int n_in,
                              void* d_out, int out_size, void* d_ws, size_t ws_size,
                              hipStream_t stream) {
  const float* hid  = (const float*)d_in[0];
  const float* mask = (const float*)d_in[1];
  const float* wq   = (const float*)d_in[2];
  const float* bq   = (const float*)d_in[3];
  const float* wk   = (const float*)d_in[4];
  const float* bk   = (const float*)d_in[5];
  const float* wv   = (const float*)d_in[6];
  const float* bv   = (const float*)d_in[7];
  const float* de   = (const float*)d_in[8];

  char* ws = (char*)d_ws;
  unsigned short* hidbf = (unsigned short*)(ws);                  // 6,291,456 B
  unsigned short* wbf   = (unsigned short*)(ws + 6291456);        // 3,538,944 B
  unsigned short* ebf   = (unsigned short*)(ws + 9830400);        //   262,144 B
  unsigned short* qb    = (unsigned short*)(ws + 10092544);       // 6,291,456 B
  unsigned short* kb    = (unsigned short*)(ws + 16384000);       // 6,291,456 B
  unsigned short* vtb   = (unsigned short*)(ws + 22675456);       // 6,291,456 B

  convert_kernel<<<4928, 256, 0, stream>>>(hid, wq, wk, wv, de, hidbf, wbf, ebf);
  qkv_gemm<<<dim3(32, 18), 256, 0, stream>>>(hidbf, wbf, bq, bk, bv, qb, kb, vtb);
  attn_kernel<<<768, 256, 0, stream>>>(qb, kb, vtb, ebf, mask, (float*)d_out);
}

// Round 13
// 171.431 us; speedup vs baseline: 1.1197x; 1.0113x over previous
//
#include <hip/hip_runtime.h>
#include <stdint.h>

// ---------------------------------------------------------------------------
// BertSelfAttention (relative_key_query) on gfx950.
// B=4 S=1024 H=768 nH=12 dH=64 MAXPOS=1024.
//   q,k,v = hidden @ W{q,k,v}.T + b        (bf16 MFMA GEMM)
//   S[l,r] = q.k + q.E[l-r+1023] + k.E[l-r+1023];  softmax(S/8 + mask) @ v
// Pipeline: convert(fp32->bf16) -> qkv_gemm -> fused flash attention.
// v14 = v13 with ONE qkv change: stage relocated to the covered slot.
//   Old: barrier -> stage(kit) -> barrier(DRAINS, 0 cover) -> frags+MFMA.
//   New: barrier(drain kit) -> frags -> barrier(reads done) ->
//        stage(kit+1, same buffer) -> MFMA (covers load latency).
//   Same 2 barriers/iter, same 32KB LDS, same occupancy — pure reorder.
//   Overwrite-safe: all ds_reads complete at barrier-2 before stage writes
//   can land; next iter's barrier-1 vmcnt(0) orders consumption.
// attn frozen at v13 (76.4us: band-cull, shear-at-write, no cvtpk/setprio).
// ---------------------------------------------------------------------------

typedef __attribute__((ext_vector_type(4))) float f32x4;
typedef __attribute__((ext_vector_type(8))) short s16x8;
typedef __attribute__((ext_vector_type(4))) short s16x4;
typedef const __attribute__((address_space(1))) void GCV;
typedef __attribute__((address_space(3))) void LDSV;

__device__ __forceinline__ unsigned short f2bf(float f) {
  union { float f; uint32_t u; } v; v.f = f;
  uint32_t r = (v.u + 0x7FFFu + ((v.u >> 16) & 1u)) >> 16;
  return (unsigned short)r;
}
__device__ __forceinline__ float bf2f(unsigned short b) {
  union { uint32_t u; float f; } v; v.u = ((uint32_t)b) << 16;
  return v.f;
}
__device__ __forceinline__ uint32_t packbf(float a, float b) {
  return (uint32_t)f2bf(a) | ((uint32_t)f2bf(b) << 16);
}

#define MFMA(a, b, c) __builtin_amdgcn_mfma_f32_16x16x32_bf16((a), (b), (c), 0, 0, 0)

// ---------------------------------------------------------------------------
// Kernel 0: fp32 -> bf16 conversion. hidden [4096x768], Wq|Wk|Wv [768x768]x3,
// dist_emb [2047x64] padded to 2048 rows (row 2047 = 0).
// ---------------------------------------------------------------------------
#define HIDQ 786432   // 4096*768/4
#define WQ4  147456   // 768*768/4
#define EQ4  32768    // 2048*64/4

__global__ __launch_bounds__(256) void convert_kernel(
    const float* __restrict__ hid, const float* __restrict__ wq,
    const float* __restrict__ wk, const float* __restrict__ wv,
    const float* __restrict__ de,
    unsigned short* __restrict__ hidbf, unsigned short* __restrict__ wbf,
    unsigned short* __restrict__ ebf) {
  int g = blockIdx.x * 256 + threadIdx.x;
  if (g < HIDQ) {
    float4 s = ((const float4*)hid)[g];
    ushort4 o; o.x = f2bf(s.x); o.y = f2bf(s.y); o.z = f2bf(s.z); o.w = f2bf(s.w);
    ((ushort4*)hidbf)[g] = o;
  } else if (g < HIDQ + 3 * WQ4) {
    int r = g - HIDQ;
    int sel = r / WQ4, r2 = r - sel * WQ4;
    const float* src = sel == 0 ? wq : (sel == 1 ? wk : wv);
    float4 s = ((const float4*)src)[r2];
    ushort4 o; o.x = f2bf(s.x); o.y = f2bf(s.y); o.z = f2bf(s.z); o.w = f2bf(s.w);
    ((ushort4*)wbf)[r] = o;
  } else {
    int r = g - HIDQ - 3 * WQ4;      // [0, 32768)
    int e = 4 * r;                   // element index into 2048*64
    ushort4 o;
    o.x = (e + 0 < 131008) ? f2bf(de[e + 0]) : 0;
    o.y = (e + 1 < 131008) ? f2bf(de[e + 1]) : 0;
    o.z = (e + 2 < 131008) ? f2bf(de[e + 2]) : 0;
    o.w = (e + 3 < 131008) ? f2bf(de[e + 3]) : 0;
    ((ushort4*)ebf)[r] = o;
  }
}

// ---------------------------------------------------------------------------
// Kernel 1: QKV projection GEMM.  C[m, o] = sum_i hid[m,i] * W[o,i] + bias[o]
// M=4096, N=2304 (q|k|v), K=768. 128x128 tile, BK=64, 4 waves (64x64 each).
// (256,3): 576 blocks all co-resident. Stage issued in the MFMA-covered slot.
// Outputs: q,k -> [bh][s][64] bf16 ; v -> transposed [bh][d][1024] bf16.
// ---------------------------------------------------------------------------
__global__ __launch_bounds__(256, 3) void qkv_gemm(
    const unsigned short* __restrict__ hidbf,   // [4096][768]
    const unsigned short* __restrict__ wbf,     // [3][768][768]
    const float* __restrict__ bq, const float* __restrict__ bk,
    const float* __restrict__ bv,
    unsigned short* __restrict__ qb, unsigned short* __restrict__ kb,
    unsigned short* __restrict__ vtb) {
  __shared__ unsigned short lda[128 * 64];   // 16KB, xor-swizzled 16B chunks
  __shared__ unsigned short ldb[128 * 64];   // 16KB
  const int tid = threadIdx.x;
  const int w = tid >> 6, lane = tid & 63, quad = lane >> 4, l15 = lane & 15;
  const int m0 = blockIdx.x * 128;
  const int bn = blockIdx.y;
  const int sel = bn / 6;
  const int nc0 = (bn - sel * 6) * 128;
  const unsigned short* wsrc = wbf + (size_t)sel * 589824;

  f32x4 acc[4][4];
#pragma unroll
  for (int i = 0; i < 4; ++i)
#pragma unroll
    for (int j = 0; j < 4; ++j) acc[i][j] = (f32x4){0.f, 0.f, 0.f, 0.f};

  const int rA = 64 * (w & 1);
  const int rB = 64 * (w >> 1);

  // stage A,B tile kit: [128 rows][64 bf16]; chunk = row*8+cp, xor swizzle
  auto stage = [&](int kit) {
    const int k0 = kit * 64;
#pragma unroll
    for (int i = 0; i < 4; ++i) {
      int cl = (w * 4 + i) * 64 + lane;
      int row = cl >> 3, cp = cl & 7, gch = cp ^ (row & 7);
      __builtin_amdgcn_global_load_lds(
          (GCV*)(hidbf + (size_t)(m0 + row) * 768 + k0 + gch * 8),
          (LDSV*)(lda + (size_t)(w * 4 + i) * 512), 16, 0, 0);
      __builtin_amdgcn_global_load_lds(
          (GCV*)(wsrc + (size_t)(nc0 + row) * 768 + k0 + gch * 8),
          (LDSV*)(ldb + (size_t)(w * 4 + i) * 512), 16, 0, 0);
    }
  };

  stage(0);   // prologue

  for (int kit = 0; kit < 12; ++kit) {
    __syncthreads();   // drains vmcnt: stage(kit) data visible

    s16x8 af[4][2], bfr[4][2];
#pragma unroll
    for (int mt = 0; mt < 4; ++mt)
#pragma unroll
      for (int ks = 0; ks < 2; ++ks) {
        int row = rA + 16 * mt + l15;
        af[mt][ks] = *(const s16x8*)(lda + row * 64 + (((quad + 4 * ks) ^ (row & 7)) * 8));
        int rowb = rB + 16 * mt + l15;
        bfr[mt][ks] = *(const s16x8*)(ldb + rowb * 64 + (((quad + 4 * ks) ^ (rowb & 7)) * 8));
      }

    __syncthreads();   // all waves' ds_reads complete -> buffers overwritable

    // issue next stage NOW: its latency is covered by the MFMA block below
    // (and by the other 2 resident blocks); drained at next top barrier.
    if (kit < 11) stage(kit + 1);

#pragma unroll
    for (int mt = 0; mt < 4; ++mt)
#pragma unroll
      for (int nt = 0; nt < 4; ++nt) {
        acc[mt][nt] = MFMA(af[mt][0], bfr[nt][0], acc[mt][nt]);
        acc[mt][nt] = MFMA(af[mt][1], bfr[nt][1], acc[mt][nt]);
      }
  }

  const float* bias = sel == 0 ? bq : (sel == 1 ? bk : bv);
#pragma unroll
  for (int nt = 0; nt < 4; ++nt) {
    int oc = nc0 + rB + 16 * nt + l15;          // [0,768)
    float bvl = bias[oc];
    int h = oc >> 6, dd = oc & 63;
#pragma unroll
    for (int mt = 0; mt < 4; ++mt) {
      int mbase = m0 + rA + 16 * mt + quad * 4;
      int b = mbase >> 10, s = mbase & 1023;
      size_t bh = (size_t)(b * 12 + h);
      if (sel < 2) {
        unsigned short* dst = (sel == 0 ? qb : kb) + bh * 65536 + (size_t)s * 64 + dd;
#pragma unroll
        for (int r = 0; r < 4; ++r) dst[(size_t)r * 64] = f2bf(acc[mt][nt][r] + bvl);
      } else {
        ushort4 pk;
        pk.x = f2bf(acc[mt][nt][0] + bvl); pk.y = f2bf(acc[mt][nt][1] + bvl);
        pk.z = f2bf(acc[mt][nt][2] + bvl); pk.w = f2bf(acc[mt][nt][3] + bvl);
        *(ushort4*)(vtb + bh * 65536 + (size_t)dd * 1024 + s) = pk;
      }
    }
  }
}

// ---------------------------------------------------------------------------
// Kernel 2: fused attention. One block = (bh, 64 q-rows). 4 waves, wave w owns
// i-strip [16w,16w+16). S computed TRANSPOSED (A=k,B=q): lane holds
// St[j=16mt+4q+r][i=l15]. Bias GEMMs Qe=q@E^T (per-wave) and Ke=k@E^T (coop,
// band-culled, balanced ownership {w, w+4}) store SHEARED [i][j] so the
// softmax gather is aligned s16x4. Max-free online softmax. PV via P through
// per-wave LDS (aliases Qe region). Manual f2bf packing (cvtpk banned: NaN).
// ---------------------------------------------------------------------------
__global__ __launch_bounds__(256, 3) void attn_kernel(
    const unsigned short* __restrict__ qb, const unsigned short* __restrict__ kb,
    const unsigned short* __restrict__ vtb, const unsigned short* __restrict__ ebf,
    const float* __restrict__ mask, float* __restrict__ out) {
  __shared__ unsigned short ksw[64 * 64];        // 8KB   swizzled
  __shared__ unsigned short vsw[64 * 64];        // 8KB   swizzled (rows = d)
  __shared__ unsigned short esw[128 * 64];       // 16KB  swizzled (rows = t)
  __shared__ unsigned short keS[64 * 68];        // 8.5KB sheared Ke[i][j], stride 68
  __shared__ unsigned short qp[4][16 * 72];      // 9KB   per-wave sheared Qe[i][j] / P[i][j]
  __shared__ unsigned short mlb[1024];           // 2KB   mask row * log2(e), bf16
  // total 51.5KB -> 3 blocks/CU

  const int tid = threadIdx.x;
  const int w = tid >> 6, lane = tid & 63, quad = lane >> 4, l15 = lane & 15;
  const int blk0 = blockIdx.x;
  const int blk = (blk0 & 7) * 96 + (blk0 >> 3);   // XCD-bijective (768 = 8*96):
  const int bh = blk >> 4;                         // all 16 l-tiles of a bh on one XCD
  const int l0 = (blk & 15) << 6;
  const int b = bh / 12;
  const int h = bh - b * 12;

  const float SC1 = 0.18033688f;   // log2(e)/8
  const float SC2 = 1.44269504f;   // log2(e)

  const unsigned short* kbh = kb + (size_t)bh * 65536;
  const unsigned short* vbh = vtb + (size_t)bh * 65536;
  unsigned short* qpw = &qp[w][0];

  // ---- staging helpers (async global->LDS, 16B/lane, xor-swizzled chunks)
  auto stage_k = [&](int r0) {
    const unsigned short* kbase = kbh + (size_t)r0 * 64;
#pragma unroll
    for (int i = 0; i < 2; ++i) {
      int cl = (w * 2 + i) * 64 + lane;
      int row = cl >> 3, cp = cl & 7, gch = cp ^ (row & 7);
      __builtin_amdgcn_global_load_lds((GCV*)(kbase + row * 64 + gch * 8),
                                       (LDSV*)(ksw + (size_t)(w * 2 + i) * 512), 16, 0, 0);
    }
  };
  auto stage_v = [&](int r0) {
    const unsigned short* vbase = vbh + r0;
#pragma unroll
    for (int i = 0; i < 2; ++i) {
      int cl = (w * 2 + i) * 64 + lane;
      int row = cl >> 3, cp = cl & 7, gch = cp ^ (row & 7);
      __builtin_amdgcn_global_load_lds((GCV*)(vbase + (size_t)row * 1024 + gch * 8),
                                       (LDSV*)(vsw + (size_t)(w * 2 + i) * 512), 16, 0, 0);
    }
  };
  auto stage_e = [&](int dbase) {
    const unsigned short* ebase = ebf + (size_t)dbase * 64;
#pragma unroll
    for (int i = 0; i < 4; ++i) {
      int cl = (w * 4 + i) * 64 + lane;
      int row = cl >> 3, cp = cl & 7, gch = cp ^ (row & 7);
      __builtin_amdgcn_global_load_lds((GCV*)(ebase + row * 64 + gch * 8),
                                       (LDSV*)(esw + (size_t)(w * 4 + i) * 512), 16, 0, 0);
    }
  };

  // stage mask row (pre-scaled by log2e, bf16); ordered by first top barrier
  {
    float4 mv = ((const float4*)(mask + (size_t)b * 1024))[tid];
    ushort4 ms;
    ms.x = f2bf(mv.x * SC2); ms.y = f2bf(mv.y * SC2);
    ms.z = f2bf(mv.z * SC2); ms.w = f2bf(mv.w * SC2);
    *(ushort4*)(mlb + tid * 4) = ms;
  }

  // q B-frags for strip row l0+16w+l15 (held all 16 iters)
  const unsigned short* qrow = qb + (size_t)bh * 65536 + (size_t)(l0 + 16 * w + l15) * 64;
  s16x8 qf[2];
  qf[0] = *(const s16x8*)(qrow + quad * 8);
  qf[1] = *(const s16x8*)(qrow + 32 + quad * 8);

  f32x4 oacc[4];
#pragma unroll
  for (int i = 0; i < 4; ++i) oacc[i] = (f32x4){0.f, 0.f, 0.f, 0.f};
  float lsum = 0.f;

  // ---- prologue: stage k/E for it=0
  stage_k(0);
  stage_e(l0 + 960);

  for (int it = 0; it < 16; ++it) {
    const int r0 = it << 6;
    __syncthreads();   // top: k/E(it) ready (vmcnt drain); all prev-iter PV reads done
    stage_v(r0);       // into single-buffer vsw; latency covered by phase1

    // ---- phase1: k A-frags (feed St and Ke)
    s16x8 kf[4][2];
#pragma unroll
    for (int mt = 0; mt < 4; ++mt)
#pragma unroll
      for (int ks = 0; ks < 2; ++ks) {
        int row = 16 * mt + l15;
        kf[mt][ks] = *(const s16x8*)(ksw + row * 64 + (((quad + 4 * ks) ^ (row & 7)) * 8));
      }

    // ---- St[j][i] = k . q
    f32x4 st[4];
#pragma unroll
    for (int mt = 0; mt < 4; ++mt) {
      f32x4 a = (f32x4){0.f, 0.f, 0.f, 0.f};
      a = MFMA(kf[mt][0], qf[0], a);
      a = MFMA(kf[mt][1], qf[1], a);
      st[mt] = a;
    }

    // ---- Qe (wave window t-tiles [w, w+4]): a[r] is Qe at
    //   (i_local = 4*quad + r, t = 16*(w+tp) + l15);  sheared col
    //   j = i + 63 - t = (4*quad + r) + 63 - 16*tp - l15   (w cancels).
    // Ke ownership: wave w owns t-tiles {w, w+4} (tp==0, tp==4) — balanced
    //   5 kept mt-loops/wave after band cull (3 <= tt+mt <= 7; computed
    //   i-range is 16(tt+mt)-63+[0,30], valid i in [0,64)).
#pragma unroll
    for (int tp = 0; tp < 5; ++tp) {
      int tt = w + tp;
      int row = 16 * tt + l15;
      s16x8 ef0 = *(const s16x8*)(esw + row * 64 + ((quad ^ (row & 7)) * 8));
      s16x8 ef1 = *(const s16x8*)(esw + row * 64 + (((quad + 4) ^ (row & 7)) * 8));
      f32x4 a = (f32x4){0.f, 0.f, 0.f, 0.f};
      a = MFMA(qf[0], ef0, a);
      a = MFMA(qf[1], ef1, a);
#pragma unroll
      for (int r = 0; r < 4; ++r) {
        int j = 4 * quad + r + 63 - 16 * tp - l15;
        if ((unsigned)j < 64u) qpw[(4 * quad + r) * 72 + j] = f2bf(a[r]);
      }
      if (tp == 0 || tp == 4) {   // this wave owns Ke t-tiles w, w+4
#pragma unroll
        for (int mt = 0; mt < 4; ++mt) {
          if (mt + tt >= 3 && mt + tt <= 7) {   // band cull (wave-uniform)
            f32x4 kacc = (f32x4){0.f, 0.f, 0.f, 0.f};
            kacc = MFMA(kf[mt][0], ef0, kacc);
            kacc = MFMA(kf[mt][1], ef1, kacc);
            int jb = 16 * mt + 4 * quad;
            int ib0 = 16 * tt + l15 + jb - 63;
#pragma unroll
            for (int r = 0; r < 4; ++r) {
              int ii = ib0 + r;
              if ((unsigned)ii < 64u) keS[ii * 68 + jb + r] = f2bf(kacc[r]);
            }
          }
        }
      }
    }
    __syncthreads();   // mid: drains vmcnt (vsw ready); keS/qp visible block-wide

    // ---- issue stage k/E for it+1 (drained at next top barrier; phase2
    // below covers the latency)
    if (it < 15) {
      stage_k(r0 + 64);
      stage_e(l0 - r0 - 64 + 960);
    }

    // ---- phase2: softmax — sheared bias rows are plain [i][j]: aligned s16x4
    float pr[4][4];
#pragma unroll
    for (int mt = 0; mt < 4; ++mt) {
      int jb = 16 * mt + 4 * quad;
      s16x4 qv4 = *(const s16x4*)(qpw + l15 * 72 + jb);
      s16x4 kv4 = *(const s16x4*)(keS + (16 * w + l15) * 68 + jb);
      s16x4 mk4 = *(const s16x4*)(mlb + r0 + jb);
#pragma unroll
      for (int r = 0; r < 4; ++r) {
        float bias = bf2f((unsigned short)qv4[r]) + bf2f((unsigned short)kv4[r]);
        float p = exp2f((st[mt][r] + bias) * SC1 + bf2f((unsigned short)mk4[r]));
        pr[mt][r] = p;
        lsum += p;
      }
    }

    // ---- P -> per-wave LDS [i=l15][j] (b64 stores; same cells the thread
    // just read as qv4 -> per-thread RAW order holds), then A-frags
#pragma unroll
    for (int mt = 0; mt < 4; ++mt) {
      uint2 pk; pk.x = packbf(pr[mt][0], pr[mt][1]); pk.y = packbf(pr[mt][2], pr[mt][3]);
      *(uint2*)(qpw + l15 * 72 + 16 * mt + 4 * quad) = pk;
    }
    s16x8 pf0 = *(const s16x8*)(qpw + l15 * 72 + quad * 8);
    s16x8 pf1 = *(const s16x8*)(qpw + l15 * 72 + 32 + quad * 8);

    // ---- O += P @ V  (B-frags from transposed V in LDS)
#pragma unroll
    for (int dt = 0; dt < 4; ++dt) {
      int row = 16 * dt + l15;
      s16x8 vf0 = *(const s16x8*)(vsw + row * 64 + ((quad ^ (row & 7)) * 8));
      s16x8 vf1 = *(const s16x8*)(vsw + row * 64 + (((quad + 4) ^ (row & 7)) * 8));
      oacc[dt] = MFMA(pf0, vf0, oacc[dt]);
      oacc[dt] = MFMA(pf1, vf1, oacc[dt]);
    }
  }

  // ---- finalize: row sums live per-lane (i=l15); combine quads, divide, store
  lsum += __shfl_xor(lsum, 16, 64);
  lsum += __shfl_xor(lsum, 32, 64);
#pragma unroll
  for (int r = 0; r < 4; ++r) {
    float ls = __shfl(lsum, quad * 4 + r, 64);
    float rinv = 1.0f / ls;
    int l = l0 + 16 * w + quad * 4 + r;
    float* dst = out + ((size_t)(b * 1024 + l)) * 768 + h * 64;
#pragma unroll
    for (int dt = 0; dt < 4; ++dt) dst[16 * dt + l15] = oacc[dt][r] * rinv;
  }
}

// ---------------------------------------------------------------------------
extern "C" void kernel_launch(void* const* d_in, const int* in_sizes, int n_in,
                              void* d_out, int out_size, void* d_ws, size_t ws_size,
                              hipStream_t stream) {
  const float* hid  = (const float*)d_in[0];
  const float* mask = (const float*)d_in[1];
  const float* wq   = (const float*)d_in[2];
  const float* bq   = (const float*)d_in[3];
  const float* wk   = (const float*)d_in[4];
  const float* bk   = (const float*)d_in[5];
  const float* wv   = (const float*)d_in[6];
  const float* bv   = (const float*)d_in[7];
  const float* de   = (const float*)d_in[8];

  char* ws = (char*)d_ws;
  unsigned short* hidbf = (unsigned short*)(ws);                  // 6,291,456 B
  unsigned short* wbf   = (unsigned short*)(ws + 6291456);        // 3,538,944 B
  unsigned short* ebf   = (unsigned short*)(ws + 9830400);        //   262,144 B
  unsigned short* qb    = (unsigned short*)(ws + 10092544);       // 6,291,456 B
  unsigned short* kb    = (unsigned short*)(ws + 16384000);       // 6,291,456 B
  unsigned short* vtb   = (unsigned short*)(ws + 22675456);       // 6,291,456 B

  convert_kernel<<<4928, 256, 0, stream>>>(hid, wq, wk, wv, de, hidbf, wbf, ebf);
  qkv_gemm<<<dim3(32, 18), 256, 0, stream>>>(hidbf, wbf, bq, bk, bv, qb, kb, vtb);
  attn_kernel<<<768, 256, 0, stream>>>(qb, kb, vtb, ebf, mask, (float*)d_out);
}